// Round 14
// baseline (508.383 us; speedup 1.0000x reference)
//
#include <hip/hip_runtime.h>
#include <math.h>

// Problem constants (match reference)
#define R_REL 2
#define IN_DIM 128
#define HID_DIM 64
#define FCOLS 128

typedef __attribute__((ext_vector_type(8))) short bf16x8;
typedef __attribute__((ext_vector_type(4))) float f32x4;

__device__ __forceinline__ ushort f2bf(float f) {
    unsigned u = __float_as_uint(f);
    u += 0x7FFFu + ((u >> 16) & 1u);   // round-to-nearest-even
    return (ushort)(u >> 16);
}

// ---------------------------------------------------------------------------
// Prep: X (n x K f32) -> bf16, coalesced.
__global__ void cvt_bf16_kernel(const float* __restrict__ in,
                                ushort* __restrict__ out, int total4) {
    int i = blockIdx.x * blockDim.x + threadIdx.x;
    if (i >= total4) return;
    float4 v = reinterpret_cast<const float4*>(in)[i];
    ushort4 o;
    o.x = f2bf(v.x); o.y = f2bf(v.y); o.z = f2bf(v.z); o.w = f2bf(v.w);
    reinterpret_cast<ushort4*>(out)[i] = o;
}

// Prep: W (R, K, FCOLS f32) -> Wt (R, FCOLS, K bf16)  (transpose + convert)
template <int K>
__global__ void wt_kernel(const float* __restrict__ W, ushort* __restrict__ Wt) {
    int i = blockIdx.x * 256 + threadIdx.x;       // grid covers R*K*FCOLS exactly
    int r = i / (K * FCOLS);
    int rem = i - r * (K * FCOLS);
    int k = rem / FCOLS, c = rem - k * FCOLS;
    Wt[((size_t)r * FCOLS + c) * K + k] = f2bf(W[i]);
}

// ---------------------------------------------------------------------------
// MFMA feat-GEMM: feat(bf16) = X (n x K) @ W (K x 128), fused el/er epilogue.
// Block: 256 thr = 4 waves, 128 nodes/block. X staged in LDS (+16B padded
// rows). W is NOT staged: Wt (16-32KB) is L1/L2-resident and shared by all
// blocks; B-fragments load directly from global (lanes tile 16 rows x 64B
// contiguous chunks). LDS 69.6->34.8KB (K=128): 2->4 blocks/CU.
// mfma_f32_16x16x32_bf16: A row=lane&15, k=(lane>>4)*8+e; B col=lane&15;
// D col=lane&15, row=(lane>>4)*4+r (verified layout, learn_hip m89).
// ---------------------------------------------------------------------------
template <int K>
__launch_bounds__(256)
__global__ void feat_gemm_mfma(const ushort* __restrict__ Xbf,
                               const ushort* __restrict__ Wt,
                               const float* __restrict__ alv,
                               const float* __restrict__ arv,
                               ushort* __restrict__ featb,
                               float* __restrict__ el,
                               float* __restrict__ er,
                               int n) {
    constexpr int S  = 2 * K + 16;   // padded row stride in bytes
    constexpr int G  = K / 8;        // 16B granules per row
    constexpr int KS = K / 32;       // mfma k-steps
    __shared__ char Xs[128 * S];
    const int tid = threadIdx.x;
    const int n0 = blockIdx.x * 128;

    for (int i = tid; i < 128 * G; i += 256) {
        int row = i / G, gk = i - row * G;
        int sr = n0 + row; if (sr >= n) sr = n - 1;
        *(uint4*)(Xs + row * S + gk * 16) =
            *(const uint4*)(Xbf + (size_t)sr * K + gk * 8);
    }
    __syncthreads();

    const int w    = tid >> 6;
    const int lane = tid & 63;
    const int c16  = lane & 15;
    const int rg   = lane >> 4;

    bf16x8 afr[2][KS];
#pragma unroll
    for (int rt = 0; rt < 2; rt++)
#pragma unroll
        for (int ks = 0; ks < KS; ks++)
            afr[rt][ks] = *(const bf16x8*)(Xs + (w * 32 + rt * 16 + c16) * S + ks * 64 + rg * 16);

    f32x4 acc[2][8];
#pragma unroll
    for (int rt = 0; rt < 2; rt++)
#pragma unroll
        for (int ct = 0; ct < 8; ct++) acc[rt][ct] = (f32x4){0.f, 0.f, 0.f, 0.f};

    const ushort* wrow = Wt + (size_t)c16 * K + rg * 8;
#pragma unroll
    for (int ct = 0; ct < 8; ct++) {
#pragma unroll
        for (int ks = 0; ks < KS; ks++) {
            bf16x8 bfr = *(const bf16x8*)(wrow + (size_t)ct * 16 * K + ks * 32);
            acc[0][ct] = __builtin_amdgcn_mfma_f32_16x16x32_bf16(afr[0][ks], bfr, acc[0][ct], 0, 0, 0);
            acc[1][ct] = __builtin_amdgcn_mfma_f32_16x16x32_bf16(afr[1][ks], bfr, acc[1][ct], 0, 0, 0);
        }
    }

    // epilogue: bf16 feat store + fused el/er
    float alq[8], arq[8];
#pragma unroll
    for (int ct = 0; ct < 8; ct++) {
        alq[ct] = alv[ct * 16 + c16];
        arq[ct] = arv[ct * 16 + c16];
    }

#pragma unroll
    for (int rt = 0; rt < 2; rt++) {
        float pel[2][4] = {{0.f,0.f,0.f,0.f},{0.f,0.f,0.f,0.f}};
        float per_[2][4] = {{0.f,0.f,0.f,0.f},{0.f,0.f,0.f,0.f}};
        const int nb = n0 + w * 32 + rt * 16 + rg * 4;  // node for r=0
#pragma unroll
        for (int ct = 0; ct < 8; ct++) {
            const int h = ct >> 2;
#pragma unroll
            for (int r = 0; r < 4; r++) {
                float v = acc[rt][ct][r];
                pel[h][r]  = fmaf(v, alq[ct], pel[h][r]);
                per_[h][r] = fmaf(v, arq[ct], per_[h][r]);
                int node = nb + r;
                if (node < n) featb[(size_t)node * 128 + ct * 16 + c16] = f2bf(v);
            }
        }
#pragma unroll
        for (int m = 8; m >= 1; m >>= 1) {
#pragma unroll
            for (int h = 0; h < 2; h++)
#pragma unroll
                for (int r = 0; r < 4; r++) {
                    pel[h][r]  += __shfl_xor(pel[h][r], m);
                    per_[h][r] += __shfl_xor(per_[h][r], m);
                }
        }
        if (c16 == 0) {
#pragma unroll
            for (int r = 0; r < 4; r++) {
                int node = nb + r;
                if (node < n) {
#pragma unroll
                    for (int h = 0; h < 2; h++) {
                        el[node * 2 + h] = pel[h][r];
                        er[node * 2 + h] = per_[h][r];
                    }
                }
            }
        }
    }
}

// ---------------------------------------------------------------------------
// CSR build over the CONCATENATED relations, XCD-partitioned (see R4 notes).
// ---------------------------------------------------------------------------
#define EDGE_CHUNK 2048

__global__ void zero_counts_kernel(int* __restrict__ counts, int n) {
    int i = blockIdx.x * blockDim.x + threadIdx.x;
    if (i < n) counts[i] = 0;
}

__global__ void count_xcd_kernel(const int* __restrict__ dst,
                                 int* __restrict__ counts,
                                 int E, int N, int kpp) {
    int part = blockIdx.x & 7;
    int base = (blockIdx.x >> 3) * EDGE_CHUNK + threadIdx.x;
    int total = 2 * E;
#pragma unroll
    for (int j = 0; j < 8; j++) {
        int i = base + j * 256;
        if (i < total) {
            int key = ((i >= E) ? N : 0) + dst[i];
            if (key / kpp == part) atomicAdd(&counts[key], 1);
        }
    }
}

#define SCAN_CHUNK 2048
#define SCAN_BT 256

__global__ void scan_blocksum_kernel(const int* __restrict__ counts,
                                     int* __restrict__ bsum, int n) {
    int b = blockIdx.x, t = threadIdx.x;
    int base = b * SCAN_CHUNK + t * 8;
    int s = 0;
#pragma unroll
    for (int j = 0; j < 8; j++) {
        int i = base + j;
        if (i < n) s += counts[i];
    }
    __shared__ int sd[SCAN_BT];
    sd[t] = s;
    __syncthreads();
    for (int off = SCAN_BT / 2; off > 0; off >>= 1) {
        if (t < off) sd[t] += sd[t + off];
        __syncthreads();
    }
    if (t == 0) bsum[b] = sd[0];
}

__global__ void scan_bsum_kernel(int* __restrict__ bsum, int* __restrict__ S,
                                 int B, int n) {
    __shared__ int sd[1024];
    int t = threadIdx.x;
    int v = (t < B) ? bsum[t] : 0;
    sd[t] = v;
    __syncthreads();
    for (int off = 1; off < 1024; off <<= 1) {
        int u = (t >= off) ? sd[t - off] : 0;
        __syncthreads();
        sd[t] = sd[t] + u;
        __syncthreads();
    }
    if (t < B) bsum[t] = sd[t] - v;
    if (t == 1023) S[n] = sd[1023];
}

__global__ void scan_write_kernel(const int* __restrict__ counts,
                                  const int* __restrict__ bsum,
                                  int* __restrict__ S, int* __restrict__ cursor,
                                  int n) {
    int b = blockIdx.x, t = threadIdx.x;
    int base = b * SCAN_CHUNK + t * 8;
    int v[8];
    int s = 0;
#pragma unroll
    for (int j = 0; j < 8; j++) {
        int i = base + j;
        v[j] = (i < n) ? counts[i] : 0;
        s += v[j];
    }
    __shared__ int sd[SCAN_BT];
    sd[t] = s;
    __syncthreads();
    for (int off = 1; off < SCAN_BT; off <<= 1) {
        int u = (t >= off) ? sd[t - off] : 0;
        __syncthreads();
        sd[t] = sd[t] + u;
        __syncthreads();
    }
    int run = bsum[b] + sd[t] - s;
#pragma unroll
    for (int j = 0; j < 8; j++) {
        int i = base + j;
        if (i < n) {
            S[i] = run;
            cursor[i] = run;
            run += v[j];
        }
    }
}

__global__ void fill_xcd_kernel(const int* __restrict__ src,
                                const int* __restrict__ dst,
                                int* __restrict__ cursor,
                                int* __restrict__ csr_src,
                                int E, int N, int kpp) {
    int part = blockIdx.x & 7;
    int base = (blockIdx.x >> 3) * EDGE_CHUNK + threadIdx.x;
    int total = 2 * E;
#pragma unroll
    for (int j = 0; j < 8; j++) {
        int i = base + j * 256;
        if (i < total) {
            int key = ((i >= E) ? N : 0) + dst[i];
            if (key / kpp == part) {
                int pos = atomicAdd(&cursor[key], 1);
                csr_src[pos] = src[i];
            }
        }
    }
}

// ---------------------------------------------------------------------------
// Fused both-relation GAT aggregation: one 64-lane wave per destination node.
// No-max softmax; LDS meta staging; unroll-8. (R13: near the gather
// throughput floor — kept as-is.)
// ---------------------------------------------------------------------------
#define AGG_BODY(J) {                                                        \
        int2 mp = lmeta[mbase + (J)];                                        \
        float a0 = __uint_as_float((unsigned)mp.y & 0xFFFF0000u);            \
        float a1 = __uint_as_float((unsigned)mp.y << 16);                    \
        den0 += a0;                                                          \
        den1 += a1;                                                          \
        float a = (h == 0) ? a0 : a1;                                        \
        unsigned fv = fbl[(size_t)mp.x * 64];                                \
        accx = fmaf(a, __uint_as_float((fv & 0xFFFFu) << 16), accx);         \
        accy = fmaf(a, __uint_as_float(fv & 0xFFFF0000u), accy);             \
    }

__launch_bounds__(256)
__global__ void gat_aggregate2_kernel(const int* __restrict__ S,
                                      const int* __restrict__ csrc,
                                      const float* __restrict__ el0,
                                      const float* __restrict__ er0,
                                      const float* __restrict__ el1,
                                      const float* __restrict__ er1,
                                      const unsigned* __restrict__ fb0,
                                      const unsigned* __restrict__ fb1,
                                      const float* __restrict__ ba,
                                      const float* __restrict__ bb,
                                      float* __restrict__ hout,
                                      int N) {
    __shared__ int2 lmeta[4 * 64];
    int node = blockIdx.x * 4 + (threadIdx.x >> 6);
    if (node >= N) return;
    int lane = threadIdx.x & 63;
    int h = lane >> 5;
    const int mbase = (threadIdx.x >> 6) * 64;

    float accTx = 0.f, accTy = 0.f;
#pragma unroll
    for (int rel = 0; rel < 2; rel++) {
        const float* el = rel ? el1 : el0;
        const float* er = rel ? er1 : er0;
        const unsigned* fbl = (rel ? fb1 : fb0) + lane;
        int rs = S[rel * N + node], re = S[rel * N + node + 1];
        float erv0 = er[node * 2], erv1 = er[node * 2 + 1];
        float accx = 0.f, accy = 0.f;
        float den0 = 0.f, den1 = 0.f;

        for (int base = rs; base < re; base += 64) {
            int c = re - base; if (c > 64) c = 64;
            int msrc = 0;
            unsigned pex = 0;
            if (lane < c) {
                msrc = csrc[base + lane];
                float2 a = *reinterpret_cast<const float2*>(el + (size_t)msrc * 2);
                float s0 = a.x + erv0; s0 = s0 > 0.f ? s0 : 0.2f * s0;
                float s1 = a.y + erv1; s1 = s1 > 0.f ? s1 : 0.2f * s1;
                pex = ((unsigned)f2bf(__expf(s0)) << 16) | (unsigned)f2bf(__expf(s1));
            }
            lmeta[mbase + lane] = make_int2(msrc, (int)pex);
            int j = 0;
            for (; j + 7 < c; j += 8) {
                AGG_BODY(j)     AGG_BODY(j + 1) AGG_BODY(j + 2) AGG_BODY(j + 3)
                AGG_BODY(j + 4) AGG_BODY(j + 5) AGG_BODY(j + 6) AGG_BODY(j + 7)
            }
            for (; j + 3 < c; j += 4) {
                AGG_BODY(j) AGG_BODY(j + 1) AGG_BODY(j + 2) AGG_BODY(j + 3)
            }
            for (; j < c; ++j) AGG_BODY(j)
        }
        float den = (h == 0) ? den0 : den1;
        float invd = (den > 0.f) ? 1.f / den : 0.f;
        accTx += accx * invd;
        accTy += accy * invd;
    }

    float2 b1v = reinterpret_cast<const float2*>(ba)[lane];
    float2 b2v = reinterpret_cast<const float2*>(bb)[lane];
    float2 o = make_float2(b1v.x + b2v.x + accTx, b1v.y + b2v.y + accTy);
    reinterpret_cast<float2*>(hout)[(size_t)node * 64 + lane] = o;
}

// ---------------------------------------------------------------------------
// Hout (n x 64) = [relu]( Hin (n x 128) @ Wl (128 x 64) + bl )
// BF16OUT: store bf16 (feeds next layer's MFMA gemm); else f32.
// ---------------------------------------------------------------------------
template <bool RELU, bool BF16OUT>
__launch_bounds__(256)
__global__ void linear_kernel(const float* __restrict__ Hin, const float* __restrict__ Wl,
                              const float* __restrict__ bl, float* __restrict__ Hout,
                              ushort* __restrict__ HoutBf, int n) {
    __shared__ float4 Wl4[128 * 16];  // 128 rows x 64 cols = 32 KB
    const int tid = threadIdx.x;
    const float4* W4 = reinterpret_cast<const float4*>(Wl);
    for (int i = tid; i < 128 * 16; i += 256) Wl4[i] = W4[i];
    __syncthreads();

    const int cg = tid & 15;   // column group (4 cols of 64)
    const int ng = tid >> 4;   // node subgroup 0..15
    const int n0 = blockIdx.x * 64 + ng * 4;

    const float4 bv = reinterpret_cast<const float4*>(bl)[cg];
    float4 acc[4];
#pragma unroll
    for (int i = 0; i < 4; i++) acc[i] = bv;

    const float4* X4 = reinterpret_cast<const float4*>(Hin);
    const float4* xrow[4];
#pragma unroll
    for (int i = 0; i < 4; i++) {
        int nn = n0 + i;
        int nc = nn < n ? nn : (n - 1);
        xrow[i] = X4 + (size_t)nc * 32;
    }

    for (int k4 = 0; k4 < 32; ++k4) {
        float4 xv[4];
#pragma unroll
        for (int i = 0; i < 4; i++) xv[i] = xrow[i][k4];
#pragma unroll
        for (int j = 0; j < 4; j++) {
            float4 wv = Wl4[(k4 * 4 + j) * 16 + cg];
#pragma unroll
            for (int i = 0; i < 4; i++) {
                float xs = (j == 0) ? xv[i].x : (j == 1) ? xv[i].y : (j == 2) ? xv[i].z : xv[i].w;
                acc[i].x = fmaf(xs, wv.x, acc[i].x);
                acc[i].y = fmaf(xs, wv.y, acc[i].y);
                acc[i].z = fmaf(xs, wv.z, acc[i].z);
                acc[i].w = fmaf(xs, wv.w, acc[i].w);
            }
        }
    }

#pragma unroll
    for (int i = 0; i < 4; i++) {
        int nn = n0 + i;
        if (nn < n) {
            float4 v = acc[i];
            if (RELU) {
                v.x = fmaxf(v.x, 0.f); v.y = fmaxf(v.y, 0.f);
                v.z = fmaxf(v.z, 0.f); v.w = fmaxf(v.w, 0.f);
            }
            if (BF16OUT) {
                ushort4 o;
                o.x = f2bf(v.x); o.y = f2bf(v.y); o.z = f2bf(v.z); o.w = f2bf(v.w);
                reinterpret_cast<ushort4*>(HoutBf)[(size_t)nn * 16 + cg] = o;
            } else {
                reinterpret_cast<float4*>(Hout)[(size_t)nn * 16 + cg] = v;
            }
        }
    }
}

// ---------------------------------------------------------------------------
extern "C" void kernel_launch(void* const* d_in, const int* in_sizes, int n_in,
                              void* d_out, int out_size, void* d_ws, size_t ws_size,
                              hipStream_t stream) {
    const float* x    = (const float*)d_in[0];
    const int*   src  = (const int*)d_in[1];
    const int*   dst  = (const int*)d_in[2];
    const float* W0   = (const float*)d_in[3];
    const float* al0  = (const float*)d_in[4];
    const float* ar0  = (const float*)d_in[5];
    const float* b0   = (const float*)d_in[6];
    const float* W1   = (const float*)d_in[7];
    const float* al1  = (const float*)d_in[8];
    const float* ar1  = (const float*)d_in[9];
    const float* b1   = (const float*)d_in[10];
    const float* linW0 = (const float*)d_in[11];
    const float* linb0 = (const float*)d_in[12];
    const float* linW1 = (const float*)d_in[13];
    const float* linb1 = (const float*)d_in[14];
    float* out = (float*)d_out;

    const int N = in_sizes[0] / IN_DIM;
    const int E = in_sizes[1] / R_REL;
    const int n2 = 2 * N;
    const int kpp = (n2 + 7) / 8;  // keys per XCD partition

    // workspace layout
    float* ws   = (float*)d_ws;
    float* hbuf = ws;                          // N*128 f32
    float* el0  = hbuf + (size_t)N * 128;      // N*2
    float* er0  = el0 + (size_t)N * 2;         // N*2
    float* el1  = er0 + (size_t)N * 2;         // N*2
    float* er1  = el1 + (size_t)N * 2;         // N*2
    ushort* Xbf    = (ushort*)(er1 + (size_t)N * 2);    // N*128 bf16
    ushort* featb0 = Xbf + (size_t)N * 128;             // N*128 bf16
    ushort* featb1 = featb0 + (size_t)N * 128;          // N*128 bf16
    ushort* hmidbf = featb1 + (size_t)N * 128;          // N*64 bf16
    ushort* Wt0    = hmidbf + (size_t)N * 64;           // 2*128*128 bf16
    ushort* Wt1    = Wt0 + (size_t)2 * FCOLS * IN_DIM;  // 2*128*64 bf16
    int* counts = (int*)(Wt1 + (size_t)2 * FCOLS * HID_DIM);  // 2N
    int* S      = counts + (size_t)n2;             // 2N+1
    int* cursor = S + (size_t)(n2 + 1);            // 2N
    int* bsum   = cursor + (size_t)n2;             // up to 1024
    int* csrsrc = bsum + 1024;                     // 2E

    const int TB = 256;
    const int bmf = (N + 127) / 128;
    const int bagg = (N + 3) / 4;
    const int blin = (N + 63) / 64;
    const int b2n = (n2 + TB - 1) / TB;
    const int nchunk = (2 * E + EDGE_CHUNK - 1) / EDGE_CHUNK;
    const int bscan = (n2 + SCAN_CHUNK - 1) / SCAN_CHUNK;

    // ---------------- prep: bf16 conversions (once per call) --------------
    const int xtotal4 = N * IN_DIM / 4;
    cvt_bf16_kernel<<<(xtotal4 + TB - 1) / TB, TB, 0, stream>>>(x, Xbf, xtotal4);
    wt_kernel<IN_DIM><<<(2 * IN_DIM * FCOLS) / 256, 256, 0, stream>>>(W0, Wt0);
    wt_kernel<HID_DIM><<<(2 * HID_DIM * FCOLS) / 256, 256, 0, stream>>>(W1, Wt1);

    // ---------------- CSR build (once; shared by both layers) -------------
    zero_counts_kernel<<<b2n, TB, 0, stream>>>(counts, n2);
    count_xcd_kernel<<<nchunk * 8, TB, 0, stream>>>(dst, counts, E, N, kpp);
    scan_blocksum_kernel<<<bscan, SCAN_BT, 0, stream>>>(counts, bsum, n2);
    scan_bsum_kernel<<<1, 1024, 0, stream>>>(bsum, S, bscan, n2);
    scan_write_kernel<<<bscan, SCAN_BT, 0, stream>>>(counts, bsum, S, cursor, n2);
    fill_xcd_kernel<<<nchunk * 8, TB, 0, stream>>>(src, dst, cursor, csrsrc, E, N, kpp);

    // ---------------- layer 0 ----------------
    feat_gemm_mfma<IN_DIM><<<bmf, TB, 0, stream>>>(Xbf, Wt0, al0, ar0, featb0, el0, er0, N);
    feat_gemm_mfma<IN_DIM><<<bmf, TB, 0, stream>>>(Xbf, Wt0 + (size_t)FCOLS * IN_DIM,
                                                   al0 + FCOLS, ar0 + FCOLS, featb1, el1, er1, N);
    gat_aggregate2_kernel<<<bagg, TB, 0, stream>>>(S, csrsrc, el0, er0, el1, er1,
                                                   (const unsigned*)featb0, (const unsigned*)featb1,
                                                   b0, b0 + 128, hbuf, N);
    linear_kernel<true, true><<<blin, TB, 0, stream>>>(hbuf, linW0, linb0, nullptr, hmidbf, N);

    // ---------------- layer 1 ----------------
    feat_gemm_mfma<HID_DIM><<<bmf, TB, 0, stream>>>(hmidbf, Wt1, al1, ar1, featb0, el0, er0, N);
    feat_gemm_mfma<HID_DIM><<<bmf, TB, 0, stream>>>(hmidbf, Wt1 + (size_t)FCOLS * HID_DIM,
                                                    al1 + FCOLS, ar1 + FCOLS, featb1, el1, er1, N);
    gat_aggregate2_kernel<<<bagg, TB, 0, stream>>>(S, csrsrc, el0, er0, el1, er1,
                                                   (const unsigned*)featb0, (const unsigned*)featb1,
                                                   b1, b1 + 128, hbuf, N);
    linear_kernel<false, false><<<blin, TB, 0, stream>>>(hbuf, linW1, linb1, out, nullptr, N);
}

// Round 15
// 480.886 us; speedup vs baseline: 1.0572x; 1.0572x over previous
//
#include <hip/hip_runtime.h>
#include <math.h>

// Problem constants (match reference)
#define R_REL 2
#define IN_DIM 128
#define HID_DIM 64
#define FCOLS 128

typedef __attribute__((ext_vector_type(8))) short bf16x8;
typedef __attribute__((ext_vector_type(4))) float f32x4;

__device__ __forceinline__ ushort f2bf(float f) {
    unsigned u = __float_as_uint(f);
    u += 0x7FFFu + ((u >> 16) & 1u);   // round-to-nearest-even
    return (ushort)(u >> 16);
}

// ---------------------------------------------------------------------------
// Prep: X (n x K f32) -> bf16, coalesced.
__global__ void cvt_bf16_kernel(const float* __restrict__ in,
                                ushort* __restrict__ out, int total4) {
    int i = blockIdx.x * blockDim.x + threadIdx.x;
    if (i >= total4) return;
    float4 v = reinterpret_cast<const float4*>(in)[i];
    ushort4 o;
    o.x = f2bf(v.x); o.y = f2bf(v.y); o.z = f2bf(v.z); o.w = f2bf(v.w);
    reinterpret_cast<ushort4*>(out)[i] = o;
}

// Prep: W (R, K, FCOLS f32) -> Wt (R, FCOLS, K bf16)  (transpose + convert)
template <int K>
__global__ void wt_kernel(const float* __restrict__ W, ushort* __restrict__ Wt) {
    int i = blockIdx.x * 256 + threadIdx.x;       // grid covers R*K*FCOLS exactly
    int r = i / (K * FCOLS);
    int rem = i - r * (K * FCOLS);
    int k = rem / FCOLS, c = rem - k * FCOLS;
    Wt[((size_t)r * FCOLS + c) * K + k] = f2bf(W[i]);
}

// ---------------------------------------------------------------------------
// MFMA feat-GEMM: feat(bf16) = X (n x K) @ W (K x 128), fused el/er epilogue.
// Block: 256 thr = 4 waves, 128 nodes/block. X and W staged in LDS, rows
// padded +16B (R14 lesson: cache-direct B-fragment loads regress vs LDS).
// mfma_f32_16x16x32_bf16: A row=lane&15, k=(lane>>4)*8+e; B col=lane&15;
// D col=lane&15, row=(lane>>4)*4+r (verified layout, learn_hip m89).
// ---------------------------------------------------------------------------
template <int K>
__launch_bounds__(256)
__global__ void feat_gemm_mfma(const ushort* __restrict__ Xbf,
                               const ushort* __restrict__ Wt,
                               const float* __restrict__ alv,
                               const float* __restrict__ arv,
                               ushort* __restrict__ featb,
                               float* __restrict__ el,
                               float* __restrict__ er,
                               int n) {
    constexpr int S  = 2 * K + 16;   // padded row stride in bytes
    constexpr int G  = K / 8;        // 16B granules per row
    constexpr int KS = K / 32;       // mfma k-steps
    __shared__ char lds[2 * 128 * S];
    char* Xs = lds;
    char* Ws = lds + 128 * S;
    const int tid = threadIdx.x;
    const int n0 = blockIdx.x * 128;

    for (int i = tid; i < 128 * G; i += 256) {
        int row = i / G, gk = i - row * G;
        int sr = n0 + row; if (sr >= n) sr = n - 1;
        *(uint4*)(Xs + row * S + gk * 16) =
            *(const uint4*)(Xbf + (size_t)sr * K + gk * 8);
    }
    for (int i = tid; i < 128 * G; i += 256) {
        int row = i / G, gk = i - row * G;
        *(uint4*)(Ws + row * S + gk * 16) =
            *(const uint4*)(Wt + (size_t)row * K + gk * 8);
    }
    __syncthreads();

    const int w    = tid >> 6;
    const int lane = tid & 63;
    const int c16  = lane & 15;
    const int rg   = lane >> 4;

    bf16x8 afr[2][KS];
#pragma unroll
    for (int rt = 0; rt < 2; rt++)
#pragma unroll
        for (int ks = 0; ks < KS; ks++)
            afr[rt][ks] = *(const bf16x8*)(Xs + (w * 32 + rt * 16 + c16) * S + ks * 64 + rg * 16);

    f32x4 acc[2][8];
#pragma unroll
    for (int rt = 0; rt < 2; rt++)
#pragma unroll
        for (int ct = 0; ct < 8; ct++) acc[rt][ct] = (f32x4){0.f, 0.f, 0.f, 0.f};

#pragma unroll
    for (int ct = 0; ct < 8; ct++) {
#pragma unroll
        for (int ks = 0; ks < KS; ks++) {
            bf16x8 bfr = *(const bf16x8*)(Ws + (ct * 16 + c16) * S + ks * 64 + rg * 16);
            acc[0][ct] = __builtin_amdgcn_mfma_f32_16x16x32_bf16(afr[0][ks], bfr, acc[0][ct], 0, 0, 0);
            acc[1][ct] = __builtin_amdgcn_mfma_f32_16x16x32_bf16(afr[1][ks], bfr, acc[1][ct], 0, 0, 0);
        }
    }

    // epilogue: bf16 feat store + fused el/er
    float alq[8], arq[8];
#pragma unroll
    for (int ct = 0; ct < 8; ct++) {
        alq[ct] = alv[ct * 16 + c16];
        arq[ct] = arv[ct * 16 + c16];
    }

#pragma unroll
    for (int rt = 0; rt < 2; rt++) {
        float pel[2][4] = {{0.f,0.f,0.f,0.f},{0.f,0.f,0.f,0.f}};
        float per_[2][4] = {{0.f,0.f,0.f,0.f},{0.f,0.f,0.f,0.f}};
        const int nb = n0 + w * 32 + rt * 16 + rg * 4;  // node for r=0
#pragma unroll
        for (int ct = 0; ct < 8; ct++) {
            const int h = ct >> 2;
#pragma unroll
            for (int r = 0; r < 4; r++) {
                float v = acc[rt][ct][r];
                pel[h][r]  = fmaf(v, alq[ct], pel[h][r]);
                per_[h][r] = fmaf(v, arq[ct], per_[h][r]);
                int node = nb + r;
                if (node < n) featb[(size_t)node * 128 + ct * 16 + c16] = f2bf(v);
            }
        }
#pragma unroll
        for (int m = 8; m >= 1; m >>= 1) {
#pragma unroll
            for (int h = 0; h < 2; h++)
#pragma unroll
                for (int r = 0; r < 4; r++) {
                    pel[h][r]  += __shfl_xor(pel[h][r], m);
                    per_[h][r] += __shfl_xor(per_[h][r], m);
                }
        }
        if (c16 == 0) {
#pragma unroll
            for (int r = 0; r < 4; r++) {
                int node = nb + r;
                if (node < n) {
#pragma unroll
                    for (int h = 0; h < 2; h++) {
                        el[node * 2 + h] = pel[h][r];
                        er[node * 2 + h] = per_[h][r];
                    }
                }
            }
        }
    }
}

// ---------------------------------------------------------------------------
// CSR build over the CONCATENATED relations, XCD-partitioned (see R4 notes).
// ---------------------------------------------------------------------------
#define EDGE_CHUNK 2048

__global__ void zero_counts_kernel(int* __restrict__ counts, int n) {
    int i = blockIdx.x * blockDim.x + threadIdx.x;
    if (i < n) counts[i] = 0;
}

__global__ void count_xcd_kernel(const int* __restrict__ dst,
                                 int* __restrict__ counts,
                                 int E, int N, int kpp) {
    int part = blockIdx.x & 7;
    int base = (blockIdx.x >> 3) * EDGE_CHUNK + threadIdx.x;
    int total = 2 * E;
#pragma unroll
    for (int j = 0; j < 8; j++) {
        int i = base + j * 256;
        if (i < total) {
            int key = ((i >= E) ? N : 0) + dst[i];
            if (key / kpp == part) atomicAdd(&counts[key], 1);
        }
    }
}

#define SCAN_CHUNK 2048
#define SCAN_BT 256

__global__ void scan_blocksum_kernel(const int* __restrict__ counts,
                                     int* __restrict__ bsum, int n) {
    int b = blockIdx.x, t = threadIdx.x;
    int base = b * SCAN_CHUNK + t * 8;
    int s = 0;
#pragma unroll
    for (int j = 0; j < 8; j++) {
        int i = base + j;
        if (i < n) s += counts[i];
    }
    __shared__ int sd[SCAN_BT];
    sd[t] = s;
    __syncthreads();
    for (int off = SCAN_BT / 2; off > 0; off >>= 1) {
        if (t < off) sd[t] += sd[t + off];
        __syncthreads();
    }
    if (t == 0) bsum[b] = sd[0];
}

__global__ void scan_bsum_kernel(int* __restrict__ bsum, int* __restrict__ S,
                                 int B, int n) {
    __shared__ int sd[1024];
    int t = threadIdx.x;
    int v = (t < B) ? bsum[t] : 0;
    sd[t] = v;
    __syncthreads();
    for (int off = 1; off < 1024; off <<= 1) {
        int u = (t >= off) ? sd[t - off] : 0;
        __syncthreads();
        sd[t] = sd[t] + u;
        __syncthreads();
    }
    if (t < B) bsum[t] = sd[t] - v;
    if (t == 1023) S[n] = sd[1023];
}

__global__ void scan_write_kernel(const int* __restrict__ counts,
                                  const int* __restrict__ bsum,
                                  int* __restrict__ S, int* __restrict__ cursor,
                                  int n) {
    int b = blockIdx.x, t = threadIdx.x;
    int base = b * SCAN_CHUNK + t * 8;
    int v[8];
    int s = 0;
#pragma unroll
    for (int j = 0; j < 8; j++) {
        int i = base + j;
        v[j] = (i < n) ? counts[i] : 0;
        s += v[j];
    }
    __shared__ int sd[SCAN_BT];
    sd[t] = s;
    __syncthreads();
    for (int off = 1; off < SCAN_BT; off <<= 1) {
        int u = (t >= off) ? sd[t - off] : 0;
        __syncthreads();
        sd[t] = sd[t] + u;
        __syncthreads();
    }
    int run = bsum[b] + sd[t] - s;
#pragma unroll
    for (int j = 0; j < 8; j++) {
        int i = base + j;
        if (i < n) {
            S[i] = run;
            cursor[i] = run;
            run += v[j];
        }
    }
}

__global__ void fill_xcd_kernel(const int* __restrict__ src,
                                const int* __restrict__ dst,
                                int* __restrict__ cursor,
                                int* __restrict__ csr_src,
                                int E, int N, int kpp) {
    int part = blockIdx.x & 7;
    int base = (blockIdx.x >> 3) * EDGE_CHUNK + threadIdx.x;
    int total = 2 * E;
#pragma unroll
    for (int j = 0; j < 8; j++) {
        int i = base + j * 256;
        if (i < total) {
            int key = ((i >= E) ? N : 0) + dst[i];
            if (key / kpp == part) {
                int pos = atomicAdd(&cursor[key], 1);
                csr_src[pos] = src[i];
            }
        }
    }
}

// ---------------------------------------------------------------------------
// Fused both-relation GAT aggregation: one 64-lane wave per destination node.
// No-max softmax; LDS meta staging; unroll-8. (R13: near the random-gather
// throughput floor — 43% HBM peak on 256B coalesced rows at random addrs.)
// ---------------------------------------------------------------------------
#define AGG_BODY(J) {                                                        \
        int2 mp = lmeta[mbase + (J)];                                        \
        float a0 = __uint_as_float((unsigned)mp.y & 0xFFFF0000u);            \
        float a1 = __uint_as_float((unsigned)mp.y << 16);                    \
        den0 += a0;                                                          \
        den1 += a1;                                                          \
        float a = (h == 0) ? a0 : a1;                                        \
        unsigned fv = fbl[(size_t)mp.x * 64];                                \
        accx = fmaf(a, __uint_as_float((fv & 0xFFFFu) << 16), accx);         \
        accy = fmaf(a, __uint_as_float(fv & 0xFFFF0000u), accy);             \
    }

__launch_bounds__(256)
__global__ void gat_aggregate2_kernel(const int* __restrict__ S,
                                      const int* __restrict__ csrc,
                                      const float* __restrict__ el0,
                                      const float* __restrict__ er0,
                                      const float* __restrict__ el1,
                                      const float* __restrict__ er1,
                                      const unsigned* __restrict__ fb0,
                                      const unsigned* __restrict__ fb1,
                                      const float* __restrict__ ba,
                                      const float* __restrict__ bb,
                                      float* __restrict__ hout,
                                      int N) {
    __shared__ int2 lmeta[4 * 64];
    int node = blockIdx.x * 4 + (threadIdx.x >> 6);
    if (node >= N) return;
    int lane = threadIdx.x & 63;
    int h = lane >> 5;
    const int mbase = (threadIdx.x >> 6) * 64;

    float accTx = 0.f, accTy = 0.f;
#pragma unroll
    for (int rel = 0; rel < 2; rel++) {
        const float* el = rel ? el1 : el0;
        const float* er = rel ? er1 : er0;
        const unsigned* fbl = (rel ? fb1 : fb0) + lane;
        int rs = S[rel * N + node], re = S[rel * N + node + 1];
        float erv0 = er[node * 2], erv1 = er[node * 2 + 1];
        float accx = 0.f, accy = 0.f;
        float den0 = 0.f, den1 = 0.f;

        for (int base = rs; base < re; base += 64) {
            int c = re - base; if (c > 64) c = 64;
            int msrc = 0;
            unsigned pex = 0;
            if (lane < c) {
                msrc = csrc[base + lane];
                float2 a = *reinterpret_cast<const float2*>(el + (size_t)msrc * 2);
                float s0 = a.x + erv0; s0 = s0 > 0.f ? s0 : 0.2f * s0;
                float s1 = a.y + erv1; s1 = s1 > 0.f ? s1 : 0.2f * s1;
                pex = ((unsigned)f2bf(__expf(s0)) << 16) | (unsigned)f2bf(__expf(s1));
            }
            lmeta[mbase + lane] = make_int2(msrc, (int)pex);
            int j = 0;
            for (; j + 7 < c; j += 8) {
                AGG_BODY(j)     AGG_BODY(j + 1) AGG_BODY(j + 2) AGG_BODY(j + 3)
                AGG_BODY(j + 4) AGG_BODY(j + 5) AGG_BODY(j + 6) AGG_BODY(j + 7)
            }
            for (; j + 3 < c; j += 4) {
                AGG_BODY(j) AGG_BODY(j + 1) AGG_BODY(j + 2) AGG_BODY(j + 3)
            }
            for (; j < c; ++j) AGG_BODY(j)
        }
        float den = (h == 0) ? den0 : den1;
        float invd = (den > 0.f) ? 1.f / den : 0.f;
        accTx += accx * invd;
        accTy += accy * invd;
    }

    float2 b1v = reinterpret_cast<const float2*>(ba)[lane];
    float2 b2v = reinterpret_cast<const float2*>(bb)[lane];
    float2 o = make_float2(b1v.x + b2v.x + accTx, b1v.y + b2v.y + accTy);
    reinterpret_cast<float2*>(hout)[(size_t)node * 64 + lane] = o;
}

// ---------------------------------------------------------------------------
// Hout (n x 64) = [relu]( Hin (n x 128) @ Wl (128 x 64) + bl )
// BF16OUT: store bf16 (feeds next layer's MFMA gemm); else f32.
// ---------------------------------------------------------------------------
template <bool RELU, bool BF16OUT>
__launch_bounds__(256)
__global__ void linear_kernel(const float* __restrict__ Hin, const float* __restrict__ Wl,
                              const float* __restrict__ bl, float* __restrict__ Hout,
                              ushort* __restrict__ HoutBf, int n) {
    __shared__ float4 Wl4[128 * 16];  // 128 rows x 64 cols = 32 KB
    const int tid = threadIdx.x;
    const float4* W4 = reinterpret_cast<const float4*>(Wl);
    for (int i = tid; i < 128 * 16; i += 256) Wl4[i] = W4[i];
    __syncthreads();

    const int cg = tid & 15;   // column group (4 cols of 64)
    const int ng = tid >> 4;   // node subgroup 0..15
    const int n0 = blockIdx.x * 64 + ng * 4;

    const float4 bv = reinterpret_cast<const float4*>(bl)[cg];
    float4 acc[4];
#pragma unroll
    for (int i = 0; i < 4; i++) acc[i] = bv;

    const float4* X4 = reinterpret_cast<const float4*>(Hin);
    const float4* xrow[4];
#pragma unroll
    for (int i = 0; i < 4; i++) {
        int nn = n0 + i;
        int nc = nn < n ? nn : (n - 1);
        xrow[i] = X4 + (size_t)nc * 32;
    }

    for (int k4 = 0; k4 < 32; ++k4) {
        float4 xv[4];
#pragma unroll
        for (int i = 0; i < 4; i++) xv[i] = xrow[i][k4];
#pragma unroll
        for (int j = 0; j < 4; j++) {
            float4 wv = Wl4[(k4 * 4 + j) * 16 + cg];
#pragma unroll
            for (int i = 0; i < 4; i++) {
                float xs = (j == 0) ? xv[i].x : (j == 1) ? xv[i].y : (j == 2) ? xv[i].z : xv[i].w;
                acc[i].x = fmaf(xs, wv.x, acc[i].x);
                acc[i].y = fmaf(xs, wv.y, acc[i].y);
                acc[i].z = fmaf(xs, wv.z, acc[i].z);
                acc[i].w = fmaf(xs, wv.w, acc[i].w);
            }
        }
    }

#pragma unroll
    for (int i = 0; i < 4; i++) {
        int nn = n0 + i;
        if (nn < n) {
            float4 v = acc[i];
            if (RELU) {
                v.x = fmaxf(v.x, 0.f); v.y = fmaxf(v.y, 0.f);
                v.z = fmaxf(v.z, 0.f); v.w = fmaxf(v.w, 0.f);
            }
            if (BF16OUT) {
                ushort4 o;
                o.x = f2bf(v.x); o.y = f2bf(v.y); o.z = f2bf(v.z); o.w = f2bf(v.w);
                reinterpret_cast<ushort4*>(HoutBf)[(size_t)nn * 16 + cg] = o;
            } else {
                reinterpret_cast<float4*>(Hout)[(size_t)nn * 16 + cg] = v;
            }
        }
    }
}

// ---------------------------------------------------------------------------
extern "C" void kernel_launch(void* const* d_in, const int* in_sizes, int n_in,
                              void* d_out, int out_size, void* d_ws, size_t ws_size,
                              hipStream_t stream) {
    const float* x    = (const float*)d_in[0];
    const int*   src  = (const int*)d_in[1];
    const int*   dst  = (const int*)d_in[2];
    const float* W0   = (const float*)d_in[3];
    const float* al0  = (const float*)d_in[4];
    const float* ar0  = (const float*)d_in[5];
    const float* b0   = (const float*)d_in[6];
    const float* W1   = (const float*)d_in[7];
    const float* al1  = (const float*)d_in[8];
    const float* ar1  = (const float*)d_in[9];
    const float* b1   = (const float*)d_in[10];
    const float* linW0 = (const float*)d_in[11];
    const float* linb0 = (const float*)d_in[12];
    const float* linW1 = (const float*)d_in[13];
    const float* linb1 = (const float*)d_in[14];
    float* out = (float*)d_out;

    const int N = in_sizes[0] / IN_DIM;
    const int E = in_sizes[1] / R_REL;
    const int n2 = 2 * N;
    const int kpp = (n2 + 7) / 8;  // keys per XCD partition

    // workspace layout
    float* ws   = (float*)d_ws;
    float* hbuf = ws;                          // N*128 f32
    float* el0  = hbuf + (size_t)N * 128;      // N*2
    float* er0  = el0 + (size_t)N * 2;         // N*2
    float* el1  = er0 + (size_t)N * 2;         // N*2
    float* er1  = el1 + (size_t)N * 2;         // N*2
    ushort* Xbf    = (ushort*)(er1 + (size_t)N * 2);    // N*128 bf16
    ushort* featb0 = Xbf + (size_t)N * 128;             // N*128 bf16
    ushort* featb1 = featb0 + (size_t)N * 128;          // N*128 bf16
    ushort* hmidbf = featb1 + (size_t)N * 128;          // N*64 bf16
    ushort* Wt0    = hmidbf + (size_t)N * 64;           // 2*128*128 bf16
    ushort* Wt1    = Wt0 + (size_t)2 * FCOLS * IN_DIM;  // 2*128*64 bf16
    int* counts = (int*)(Wt1 + (size_t)2 * FCOLS * HID_DIM);  // 2N
    int* S      = counts + (size_t)n2;             // 2N+1
    int* cursor = S + (size_t)(n2 + 1);            // 2N
    int* bsum   = cursor + (size_t)n2;             // up to 1024
    int* csrsrc = bsum + 1024;                     // 2E

    const int TB = 256;
    const int bmf = (N + 127) / 128;
    const int bagg = (N + 3) / 4;
    const int blin = (N + 63) / 64;
    const int b2n = (n2 + TB - 1) / TB;
    const int nchunk = (2 * E + EDGE_CHUNK - 1) / EDGE_CHUNK;
    const int bscan = (n2 + SCAN_CHUNK - 1) / SCAN_CHUNK;

    // ---------------- prep: bf16 conversions (once per call) --------------
    const int xtotal4 = N * IN_DIM / 4;
    cvt_bf16_kernel<<<(xtotal4 + TB - 1) / TB, TB, 0, stream>>>(x, Xbf, xtotal4);
    wt_kernel<IN_DIM><<<(2 * IN_DIM * FCOLS) / 256, 256, 0, stream>>>(W0, Wt0);
    wt_kernel<HID_DIM><<<(2 * HID_DIM * FCOLS) / 256, 256, 0, stream>>>(W1, Wt1);

    // ---------------- CSR build (once; shared by both layers) -------------
    zero_counts_kernel<<<b2n, TB, 0, stream>>>(counts, n2);
    count_xcd_kernel<<<nchunk * 8, TB, 0, stream>>>(dst, counts, E, N, kpp);
    scan_blocksum_kernel<<<bscan, SCAN_BT, 0, stream>>>(counts, bsum, n2);
    scan_bsum_kernel<<<1, 1024, 0, stream>>>(bsum, S, bscan, n2);
    scan_write_kernel<<<bscan, SCAN_BT, 0, stream>>>(counts, bsum, S, cursor, n2);
    fill_xcd_kernel<<<nchunk * 8, TB, 0, stream>>>(src, dst, cursor, csrsrc, E, N, kpp);

    // ---------------- layer 0 ----------------
    feat_gemm_mfma<IN_DIM><<<bmf, TB, 0, stream>>>(Xbf, Wt0, al0, ar0, featb0, el0, er0, N);
    feat_gemm_mfma<IN_DIM><<<bmf, TB, 0, stream>>>(Xbf, Wt0 + (size_t)FCOLS * IN_DIM,
                                                   al0 + FCOLS, ar0 + FCOLS, featb1, el1, er1, N);
    gat_aggregate2_kernel<<<bagg, TB, 0, stream>>>(S, csrsrc, el0, er0, el1, er1,
                                                   (const unsigned*)featb0, (const unsigned*)featb1,
                                                   b0, b0 + 128, hbuf, N);
    linear_kernel<true, true><<<blin, TB, 0, stream>>>(hbuf, linW0, linb0, nullptr, hmidbf, N);

    // ---------------- layer 1 ----------------
    feat_gemm_mfma<HID_DIM><<<bmf, TB, 0, stream>>>(hmidbf, Wt1, al1, ar1, featb0, el0, er0, N);
    feat_gemm_mfma<HID_DIM><<<bmf, TB, 0, stream>>>(hmidbf, Wt1 + (size_t)FCOLS * HID_DIM,
                                                    al1 + FCOLS, ar1 + FCOLS, featb1, el1, er1, N);
    gat_aggregate2_kernel<<<bagg, TB, 0, stream>>>(S, csrsrc, el0, er0, el1, er1,
                                                   (const unsigned*)featb0, (const unsigned*)featb1,
                                                   b1, b1 + 128, hbuf, N);
    linear_kernel<false, false><<<blin, TB, 0, stream>>>(hbuf, linW1, linb1, out, nullptr, N);
}

// Round 16
// 473.203 us; speedup vs baseline: 1.0743x; 1.0162x over previous
//
#include <hip/hip_runtime.h>
#include <math.h>

// Problem constants (match reference)
#define R_REL 2
#define IN_DIM 128
#define HID_DIM 64
#define FCOLS 128

typedef __attribute__((ext_vector_type(8))) short bf16x8;
typedef __attribute__((ext_vector_type(4))) float f32x4;

__device__ __forceinline__ ushort f2bf(float f) {
    unsigned u = __float_as_uint(f);
    u += 0x7FFFu + ((u >> 16) & 1u);   // round-to-nearest-even
    return (ushort)(u >> 16);
}

// ---------------------------------------------------------------------------
// Prep: X (n x K f32) -> bf16, coalesced.
__global__ void cvt_bf16_kernel(const float* __restrict__ in,
                                ushort* __restrict__ out, int total4) {
    int i = blockIdx.x * blockDim.x + threadIdx.x;
    if (i >= total4) return;
    float4 v = reinterpret_cast<const float4*>(in)[i];
    ushort4 o;
    o.x = f2bf(v.x); o.y = f2bf(v.y); o.z = f2bf(v.z); o.w = f2bf(v.w);
    reinterpret_cast<ushort4*>(out)[i] = o;
}

// Prep: W (R, K, FCOLS f32) -> Wt (R, FCOLS, K bf16)  (transpose + convert)
template <int K>
__global__ void wt_kernel(const float* __restrict__ W, ushort* __restrict__ Wt) {
    int i = blockIdx.x * 256 + threadIdx.x;       // grid covers R*K*FCOLS exactly
    int r = i / (K * FCOLS);
    int rem = i - r * (K * FCOLS);
    int k = rem / FCOLS, c = rem - k * FCOLS;
    Wt[((size_t)r * FCOLS + c) * K + k] = f2bf(W[i]);
}

// ---------------------------------------------------------------------------
// MFMA feat-GEMM: feat(bf16) = X (n x K) @ W (K x 128), fused el/er epilogue.
// Block: 256 thr = 4 waves, 128 nodes/block. X and W staged in LDS, rows
// padded +16B (R14 lesson: cache-direct B-fragment loads regress vs LDS).
// mfma_f32_16x16x32_bf16: A row=lane&15, k=(lane>>4)*8+e; B col=lane&15;
// D col=lane&15, row=(lane>>4)*4+r (verified layout, learn_hip m89).
// ---------------------------------------------------------------------------
template <int K>
__launch_bounds__(256)
__global__ void feat_gemm_mfma(const ushort* __restrict__ Xbf,
                               const ushort* __restrict__ Wt,
                               const float* __restrict__ alv,
                               const float* __restrict__ arv,
                               ushort* __restrict__ featb,
                               float* __restrict__ el,
                               float* __restrict__ er,
                               int n) {
    constexpr int S  = 2 * K + 16;   // padded row stride in bytes
    constexpr int G  = K / 8;        // 16B granules per row
    constexpr int KS = K / 32;       // mfma k-steps
    __shared__ char lds[2 * 128 * S];
    char* Xs = lds;
    char* Ws = lds + 128 * S;
    const int tid = threadIdx.x;
    const int n0 = blockIdx.x * 128;

    for (int i = tid; i < 128 * G; i += 256) {
        int row = i / G, gk = i - row * G;
        int sr = n0 + row; if (sr >= n) sr = n - 1;
        *(uint4*)(Xs + row * S + gk * 16) =
            *(const uint4*)(Xbf + (size_t)sr * K + gk * 8);
    }
    for (int i = tid; i < 128 * G; i += 256) {
        int row = i / G, gk = i - row * G;
        *(uint4*)(Ws + row * S + gk * 16) =
            *(const uint4*)(Wt + (size_t)row * K + gk * 8);
    }
    __syncthreads();

    const int w    = tid >> 6;
    const int lane = tid & 63;
    const int c16  = lane & 15;
    const int rg   = lane >> 4;

    bf16x8 afr[2][KS];
#pragma unroll
    for (int rt = 0; rt < 2; rt++)
#pragma unroll
        for (int ks = 0; ks < KS; ks++)
            afr[rt][ks] = *(const bf16x8*)(Xs + (w * 32 + rt * 16 + c16) * S + ks * 64 + rg * 16);

    f32x4 acc[2][8];
#pragma unroll
    for (int rt = 0; rt < 2; rt++)
#pragma unroll
        for (int ct = 0; ct < 8; ct++) acc[rt][ct] = (f32x4){0.f, 0.f, 0.f, 0.f};

#pragma unroll
    for (int ct = 0; ct < 8; ct++) {
#pragma unroll
        for (int ks = 0; ks < KS; ks++) {
            bf16x8 bfr = *(const bf16x8*)(Ws + (ct * 16 + c16) * S + ks * 64 + rg * 16);
            acc[0][ct] = __builtin_amdgcn_mfma_f32_16x16x32_bf16(afr[0][ks], bfr, acc[0][ct], 0, 0, 0);
            acc[1][ct] = __builtin_amdgcn_mfma_f32_16x16x32_bf16(afr[1][ks], bfr, acc[1][ct], 0, 0, 0);
        }
    }

    // epilogue: bf16 feat store + fused el/er
    float alq[8], arq[8];
#pragma unroll
    for (int ct = 0; ct < 8; ct++) {
        alq[ct] = alv[ct * 16 + c16];
        arq[ct] = arv[ct * 16 + c16];
    }

#pragma unroll
    for (int rt = 0; rt < 2; rt++) {
        float pel[2][4] = {{0.f,0.f,0.f,0.f},{0.f,0.f,0.f,0.f}};
        float per_[2][4] = {{0.f,0.f,0.f,0.f},{0.f,0.f,0.f,0.f}};
        const int nb = n0 + w * 32 + rt * 16 + rg * 4;  // node for r=0
#pragma unroll
        for (int ct = 0; ct < 8; ct++) {
            const int h = ct >> 2;
#pragma unroll
            for (int r = 0; r < 4; r++) {
                float v = acc[rt][ct][r];
                pel[h][r]  = fmaf(v, alq[ct], pel[h][r]);
                per_[h][r] = fmaf(v, arq[ct], per_[h][r]);
                int node = nb + r;
                if (node < n) featb[(size_t)node * 128 + ct * 16 + c16] = f2bf(v);
            }
        }
#pragma unroll
        for (int m = 8; m >= 1; m >>= 1) {
#pragma unroll
            for (int h = 0; h < 2; h++)
#pragma unroll
                for (int r = 0; r < 4; r++) {
                    pel[h][r]  += __shfl_xor(pel[h][r], m);
                    per_[h][r] += __shfl_xor(per_[h][r], m);
                }
        }
        if (c16 == 0) {
#pragma unroll
            for (int r = 0; r < 4; r++) {
                int node = nb + r;
                if (node < n) {
#pragma unroll
                    for (int h = 0; h < 2; h++) {
                        el[node * 2 + h] = pel[h][r];
                        er[node * 2 + h] = per_[h][r];
                    }
                }
            }
        }
    }
}

// ---------------------------------------------------------------------------
// CSR build over the CONCATENATED relations, XCD-partitioned (see R4 notes).
// ---------------------------------------------------------------------------
#define EDGE_CHUNK 2048

__global__ void zero_counts_kernel(int* __restrict__ counts, int n) {
    int i = blockIdx.x * blockDim.x + threadIdx.x;
    if (i < n) counts[i] = 0;
}

__global__ void count_xcd_kernel(const int* __restrict__ dst,
                                 int* __restrict__ counts,
                                 int E, int N, int kpp) {
    int part = blockIdx.x & 7;
    int base = (blockIdx.x >> 3) * EDGE_CHUNK + threadIdx.x;
    int total = 2 * E;
#pragma unroll
    for (int j = 0; j < 8; j++) {
        int i = base + j * 256;
        if (i < total) {
            int key = ((i >= E) ? N : 0) + dst[i];
            if (key / kpp == part) atomicAdd(&counts[key], 1);
        }
    }
}

#define SCAN_CHUNK 2048
#define SCAN_BT 256

__global__ void scan_blocksum_kernel(const int* __restrict__ counts,
                                     int* __restrict__ bsum, int n) {
    int b = blockIdx.x, t = threadIdx.x;
    int base = b * SCAN_CHUNK + t * 8;
    int s = 0;
#pragma unroll
    for (int j = 0; j < 8; j++) {
        int i = base + j;
        if (i < n) s += counts[i];
    }
    __shared__ int sd[SCAN_BT];
    sd[t] = s;
    __syncthreads();
    for (int off = SCAN_BT / 2; off > 0; off >>= 1) {
        if (t < off) sd[t] += sd[t + off];
        __syncthreads();
    }
    if (t == 0) bsum[b] = sd[0];
}

__global__ void scan_bsum_kernel(int* __restrict__ bsum, int* __restrict__ S,
                                 int B, int n) {
    __shared__ int sd[1024];
    int t = threadIdx.x;
    int v = (t < B) ? bsum[t] : 0;
    sd[t] = v;
    __syncthreads();
    for (int off = 1; off < 1024; off <<= 1) {
        int u = (t >= off) ? sd[t - off] : 0;
        __syncthreads();
        sd[t] = sd[t] + u;
        __syncthreads();
    }
    if (t < B) bsum[t] = sd[t] - v;
    if (t == 1023) S[n] = sd[1023];
}

__global__ void scan_write_kernel(const int* __restrict__ counts,
                                  const int* __restrict__ bsum,
                                  int* __restrict__ S, int* __restrict__ cursor,
                                  int n) {
    int b = blockIdx.x, t = threadIdx.x;
    int base = b * SCAN_CHUNK + t * 8;
    int v[8];
    int s = 0;
#pragma unroll
    for (int j = 0; j < 8; j++) {
        int i = base + j;
        v[j] = (i < n) ? counts[i] : 0;
        s += v[j];
    }
    __shared__ int sd[SCAN_BT];
    sd[t] = s;
    __syncthreads();
    for (int off = 1; off < SCAN_BT; off <<= 1) {
        int u = (t >= off) ? sd[t - off] : 0;
        __syncthreads();
        sd[t] = sd[t] + u;
        __syncthreads();
    }
    int run = bsum[b] + sd[t] - s;
#pragma unroll
    for (int j = 0; j < 8; j++) {
        int i = base + j;
        if (i < n) {
            S[i] = run;
            cursor[i] = run;
            run += v[j];
        }
    }
}

__global__ void fill_xcd_kernel(const int* __restrict__ src,
                                const int* __restrict__ dst,
                                int* __restrict__ cursor,
                                int* __restrict__ csr_src,
                                int E, int N, int kpp) {
    int part = blockIdx.x & 7;
    int base = (blockIdx.x >> 3) * EDGE_CHUNK + threadIdx.x;
    int total = 2 * E;
#pragma unroll
    for (int j = 0; j < 8; j++) {
        int i = base + j * 256;
        if (i < total) {
            int key = ((i >= E) ? N : 0) + dst[i];
            if (key / kpp == part) {
                int pos = atomicAdd(&cursor[key], 1);
                csr_src[pos] = src[i];
            }
        }
    }
}

// ---------------------------------------------------------------------------
// Fused both-relation GAT aggregation: one 64-lane wave per destination node.
// No-max softmax; LDS meta staging; unroll-8. Output packed 2xbf16 per lane
// (halves hbuf write traffic; linear reads bf16).
// ---------------------------------------------------------------------------
#define AGG_BODY(J) {                                                        \
        int2 mp = lmeta[mbase + (J)];                                        \
        float a0 = __uint_as_float((unsigned)mp.y & 0xFFFF0000u);            \
        float a1 = __uint_as_float((unsigned)mp.y << 16);                    \
        den0 += a0;                                                          \
        den1 += a1;                                                          \
        float a = (h == 0) ? a0 : a1;                                        \
        unsigned fv = fbl[(size_t)mp.x * 64];                                \
        accx = fmaf(a, __uint_as_float((fv & 0xFFFFu) << 16), accx);         \
        accy = fmaf(a, __uint_as_float(fv & 0xFFFF0000u), accy);             \
    }

__launch_bounds__(256)
__global__ void gat_aggregate2_kernel(const int* __restrict__ S,
                                      const int* __restrict__ csrc,
                                      const float* __restrict__ el0,
                                      const float* __restrict__ er0,
                                      const float* __restrict__ el1,
                                      const float* __restrict__ er1,
                                      const unsigned* __restrict__ fb0,
                                      const unsigned* __restrict__ fb1,
                                      const float* __restrict__ ba,
                                      const float* __restrict__ bb,
                                      unsigned* __restrict__ hout,
                                      int N) {
    __shared__ int2 lmeta[4 * 64];
    int node = blockIdx.x * 4 + (threadIdx.x >> 6);
    if (node >= N) return;
    int lane = threadIdx.x & 63;
    int h = lane >> 5;
    const int mbase = (threadIdx.x >> 6) * 64;

    float accTx = 0.f, accTy = 0.f;
#pragma unroll
    for (int rel = 0; rel < 2; rel++) {
        const float* el = rel ? el1 : el0;
        const float* er = rel ? er1 : er0;
        const unsigned* fbl = (rel ? fb1 : fb0) + lane;
        int rs = S[rel * N + node], re = S[rel * N + node + 1];
        float erv0 = er[node * 2], erv1 = er[node * 2 + 1];
        float accx = 0.f, accy = 0.f;
        float den0 = 0.f, den1 = 0.f;

        for (int base = rs; base < re; base += 64) {
            int c = re - base; if (c > 64) c = 64;
            int msrc = 0;
            unsigned pex = 0;
            if (lane < c) {
                msrc = csrc[base + lane];
                float2 a = *reinterpret_cast<const float2*>(el + (size_t)msrc * 2);
                float s0 = a.x + erv0; s0 = s0 > 0.f ? s0 : 0.2f * s0;
                float s1 = a.y + erv1; s1 = s1 > 0.f ? s1 : 0.2f * s1;
                pex = ((unsigned)f2bf(__expf(s0)) << 16) | (unsigned)f2bf(__expf(s1));
            }
            lmeta[mbase + lane] = make_int2(msrc, (int)pex);
            int j = 0;
            for (; j + 7 < c; j += 8) {
                AGG_BODY(j)     AGG_BODY(j + 1) AGG_BODY(j + 2) AGG_BODY(j + 3)
                AGG_BODY(j + 4) AGG_BODY(j + 5) AGG_BODY(j + 6) AGG_BODY(j + 7)
            }
            for (; j + 3 < c; j += 4) {
                AGG_BODY(j) AGG_BODY(j + 1) AGG_BODY(j + 2) AGG_BODY(j + 3)
            }
            for (; j < c; ++j) AGG_BODY(j)
        }
        float den = (h == 0) ? den0 : den1;
        float invd = (den > 0.f) ? 1.f / den : 0.f;
        accTx += accx * invd;
        accTy += accy * invd;
    }

    float2 b1v = reinterpret_cast<const float2*>(ba)[lane];
    float2 b2v = reinterpret_cast<const float2*>(bb)[lane];
    float ox = b1v.x + b2v.x + accTx;
    float oy = b1v.y + b2v.y + accTy;
    hout[(size_t)node * 64 + lane] =
        ((unsigned)f2bf(oy) << 16) | (unsigned)f2bf(ox);
}

// ---------------------------------------------------------------------------
// Hout (n x 64) = [relu]( Hin(bf16, n x 128) @ Wl (128 x 64) + bl )
// BF16OUT: store bf16 (feeds next layer's MFMA gemm); else f32.
// ---------------------------------------------------------------------------
template <bool RELU, bool BF16OUT>
__launch_bounds__(256)
__global__ void linear_kernel(const ushort* __restrict__ Hin, const float* __restrict__ Wl,
                              const float* __restrict__ bl, float* __restrict__ Hout,
                              ushort* __restrict__ HoutBf, int n) {
    __shared__ float4 Wl4[128 * 16];  // 128 rows x 64 cols = 32 KB
    const int tid = threadIdx.x;
    const float4* W4 = reinterpret_cast<const float4*>(Wl);
    for (int i = tid; i < 128 * 16; i += 256) Wl4[i] = W4[i];
    __syncthreads();

    const int cg = tid & 15;   // column group (4 cols of 64)
    const int ng = tid >> 4;   // node subgroup 0..15
    const int n0 = blockIdx.x * 64 + ng * 4;

    const float4 bv = reinterpret_cast<const float4*>(bl)[cg];
    float4 acc[4];
#pragma unroll
    for (int i = 0; i < 4; i++) acc[i] = bv;

    const uint4* xrow[4];
#pragma unroll
    for (int i = 0; i < 4; i++) {
        int nn = n0 + i;
        int nc = nn < n ? nn : (n - 1);
        xrow[i] = reinterpret_cast<const uint4*>(Hin + (size_t)nc * 128);  // 16 uint4/row
    }

    for (int g = 0; g < 16; ++g) {   // 8 bf16 elems per granule
        uint4 xv[4];
#pragma unroll
        for (int i = 0; i < 4; i++) xv[i] = xrow[i][g];
#pragma unroll
        for (int j = 0; j < 8; j++) {
            float4 wv = Wl4[(g * 8 + j) * 16 + cg];
#pragma unroll
            for (int i = 0; i < 4; i++) {
                unsigned word = (j >> 1) == 0 ? xv[i].x : (j >> 1) == 1 ? xv[i].y
                              : (j >> 1) == 2 ? xv[i].z : xv[i].w;
                float xs = __uint_as_float((j & 1) ? (word & 0xFFFF0000u) : (word << 16));
                acc[i].x = fmaf(xs, wv.x, acc[i].x);
                acc[i].y = fmaf(xs, wv.y, acc[i].y);
                acc[i].z = fmaf(xs, wv.z, acc[i].z);
                acc[i].w = fmaf(xs, wv.w, acc[i].w);
            }
        }
    }

#pragma unroll
    for (int i = 0; i < 4; i++) {
        int nn = n0 + i;
        if (nn < n) {
            float4 v = acc[i];
            if (RELU) {
                v.x = fmaxf(v.x, 0.f); v.y = fmaxf(v.y, 0.f);
                v.z = fmaxf(v.z, 0.f); v.w = fmaxf(v.w, 0.f);
            }
            if (BF16OUT) {
                ushort4 o;
                o.x = f2bf(v.x); o.y = f2bf(v.y); o.z = f2bf(v.z); o.w = f2bf(v.w);
                reinterpret_cast<ushort4*>(HoutBf)[(size_t)nn * 16 + cg] = o;
            } else {
                reinterpret_cast<float4*>(Hout)[(size_t)nn * 16 + cg] = v;
            }
        }
    }
}

// ---------------------------------------------------------------------------
extern "C" void kernel_launch(void* const* d_in, const int* in_sizes, int n_in,
                              void* d_out, int out_size, void* d_ws, size_t ws_size,
                              hipStream_t stream) {
    const float* x    = (const float*)d_in[0];
    const int*   src  = (const int*)d_in[1];
    const int*   dst  = (const int*)d_in[2];
    const float* W0   = (const float*)d_in[3];
    const float* al0  = (const float*)d_in[4];
    const float* ar0  = (const float*)d_in[5];
    const float* b0   = (const float*)d_in[6];
    const float* W1   = (const float*)d_in[7];
    const float* al1  = (const float*)d_in[8];
    const float* ar1  = (const float*)d_in[9];
    const float* b1   = (const float*)d_in[10];
    const float* linW0 = (const float*)d_in[11];
    const float* linb0 = (const float*)d_in[12];
    const float* linW1 = (const float*)d_in[13];
    const float* linb1 = (const float*)d_in[14];
    float* out = (float*)d_out;

    const int N = in_sizes[0] / IN_DIM;
    const int E = in_sizes[1] / R_REL;
    const int n2 = 2 * N;
    const int kpp = (n2 + 7) / 8;  // keys per XCD partition

    // workspace layout (hbuf slot kept at N*128 floats; only half used now)
    float* ws   = (float*)d_ws;
    float* hbuf = ws;                          // N*64 uint (2xbf16 packed)
    float* el0  = hbuf + (size_t)N * 128;      // N*2
    float* er0  = el0 + (size_t)N * 2;         // N*2
    float* el1  = er0 + (size_t)N * 2;         // N*2
    float* er1  = el1 + (size_t)N * 2;         // N*2
    ushort* Xbf    = (ushort*)(er1 + (size_t)N * 2);    // N*128 bf16
    ushort* featb0 = Xbf + (size_t)N * 128;             // N*128 bf16
    ushort* featb1 = featb0 + (size_t)N * 128;          // N*128 bf16
    ushort* hmidbf = featb1 + (size_t)N * 128;          // N*64 bf16
    ushort* Wt0    = hmidbf + (size_t)N * 64;           // 2*128*128 bf16
    ushort* Wt1    = Wt0 + (size_t)2 * FCOLS * IN_DIM;  // 2*128*64 bf16
    int* counts = (int*)(Wt1 + (size_t)2 * FCOLS * HID_DIM);  // 2N
    int* S      = counts + (size_t)n2;             // 2N+1
    int* cursor = S + (size_t)(n2 + 1);            // 2N
    int* bsum   = cursor + (size_t)n2;             // up to 1024
    int* csrsrc = bsum + 1024;                     // 2E

    const int TB = 256;
    const int bmf = (N + 127) / 128;
    const int bagg = (N + 3) / 4;
    const int blin = (N + 63) / 64;
    const int b2n = (n2 + TB - 1) / TB;
    const int nchunk = (2 * E + EDGE_CHUNK - 1) / EDGE_CHUNK;
    const int bscan = (n2 + SCAN_CHUNK - 1) / SCAN_CHUNK;

    // ---------------- prep: bf16 conversions (once per call) --------------
    const int xtotal4 = N * IN_DIM / 4;
    cvt_bf16_kernel<<<(xtotal4 + TB - 1) / TB, TB, 0, stream>>>(x, Xbf, xtotal4);
    wt_kernel<IN_DIM><<<(2 * IN_DIM * FCOLS) / 256, 256, 0, stream>>>(W0, Wt0);
    wt_kernel<HID_DIM><<<(2 * HID_DIM * FCOLS) / 256, 256, 0, stream>>>(W1, Wt1);

    // ---------------- CSR build (once; shared by both layers) -------------
    zero_counts_kernel<<<b2n, TB, 0, stream>>>(counts, n2);
    count_xcd_kernel<<<nchunk * 8, TB, 0, stream>>>(dst, counts, E, N, kpp);
    scan_blocksum_kernel<<<bscan, SCAN_BT, 0, stream>>>(counts, bsum, n2);
    scan_bsum_kernel<<<1, 1024, 0, stream>>>(bsum, S, bscan, n2);
    scan_write_kernel<<<bscan, SCAN_BT, 0, stream>>>(counts, bsum, S, cursor, n2);
    fill_xcd_kernel<<<nchunk * 8, TB, 0, stream>>>(src, dst, cursor, csrsrc, E, N, kpp);

    // ---------------- layer 0 ----------------
    feat_gemm_mfma<IN_DIM><<<bmf, TB, 0, stream>>>(Xbf, Wt0, al0, ar0, featb0, el0, er0, N);
    feat_gemm_mfma<IN_DIM><<<bmf, TB, 0, stream>>>(Xbf, Wt0 + (size_t)FCOLS * IN_DIM,
                                                   al0 + FCOLS, ar0 + FCOLS, featb1, el1, er1, N);
    gat_aggregate2_kernel<<<bagg, TB, 0, stream>>>(S, csrsrc, el0, er0, el1, er1,
                                                   (const unsigned*)featb0, (const unsigned*)featb1,
                                                   b0, b0 + 128, (unsigned*)hbuf, N);
    linear_kernel<true, true><<<blin, TB, 0, stream>>>((const ushort*)hbuf, linW0, linb0,
                                                       nullptr, hmidbf, N);

    // ---------------- layer 1 ----------------
    feat_gemm_mfma<HID_DIM><<<bmf, TB, 0, stream>>>(hmidbf, Wt1, al1, ar1, featb0, el0, er0, N);
    feat_gemm_mfma<HID_DIM><<<bmf, TB, 0, stream>>>(hmidbf, Wt1 + (size_t)FCOLS * HID_DIM,
                                                    al1 + FCOLS, ar1 + FCOLS, featb1, el1, er1, N);
    gat_aggregate2_kernel<<<bagg, TB, 0, stream>>>(S, csrsrc, el0, er0, el1, er1,
                                                   (const unsigned*)featb0, (const unsigned*)featb1,
                                                   b1, b1 + 128, (unsigned*)hbuf, N);
    linear_kernel<false, false><<<blin, TB, 0, stream>>>((const ushort*)hbuf, linW1, linb1,
                                                         out, nullptr, N);
}

// Round 17
// 457.540 us; speedup vs baseline: 1.1111x; 1.0342x over previous
//
#include <hip/hip_runtime.h>
#include <math.h>

// Problem constants (match reference)
#define R_REL 2
#define IN_DIM 128
#define HID_DIM 64
#define FCOLS 128

typedef __attribute__((ext_vector_type(8))) short bf16x8;
typedef __attribute__((ext_vector_type(4))) float f32x4;

__device__ __forceinline__ ushort f2bf(float f) {
    unsigned u = __float_as_uint(f);
    u += 0x7FFFu + ((u >> 16) & 1u);   // round-to-nearest-even
    return (ushort)(u >> 16);
}

// ---------------------------------------------------------------------------
// Prep: X (n x K f32) -> bf16, coalesced.
__global__ void cvt_bf16_kernel(const float* __restrict__ in,
                                ushort* __restrict__ out, int total4) {
    int i = blockIdx.x * blockDim.x + threadIdx.x;
    if (i >= total4) return;
    float4 v = reinterpret_cast<const float4*>(in)[i];
    ushort4 o;
    o.x = f2bf(v.x); o.y = f2bf(v.y); o.z = f2bf(v.z); o.w = f2bf(v.w);
    reinterpret_cast<ushort4*>(out)[i] = o;
}

// Prep: W (R, K, FCOLS f32) -> Wt (R, FCOLS, K bf16)  (transpose + convert)
template <int K>
__global__ void wt_kernel(const float* __restrict__ W, ushort* __restrict__ Wt) {
    int i = blockIdx.x * 256 + threadIdx.x;       // grid covers R*K*FCOLS exactly
    int r = i / (K * FCOLS);
    int rem = i - r * (K * FCOLS);
    int k = rem / FCOLS, c = rem - k * FCOLS;
    Wt[((size_t)r * FCOLS + c) * K + k] = f2bf(W[i]);
}

// ---------------------------------------------------------------------------
// Fused both-relation MFMA feat-GEMM: feat_r(bf16) = X @ W_r, r=0,1, with
// fused el/er epilogues. X staged ONCE in LDS and A-fragments loaded ONCE
// into registers (relation-invariant); per relation only W is re-staged.
// Saves a full X global read + LDS staging pass + one dispatch per layer.
// Block: 256 thr = 4 waves, 128 nodes/block; rows padded +16B.
// mfma_f32_16x16x32_bf16: A row=lane&15, k=(lane>>4)*8+e; B col=lane&15;
// D col=lane&15, row=(lane>>4)*4+r (verified layout, learn_hip m89).
// ---------------------------------------------------------------------------
template <int K>
__launch_bounds__(256)
__global__ void feat_gemm_mfma2(const ushort* __restrict__ Xbf,
                                const ushort* __restrict__ Wt,   // both relations
                                const float* __restrict__ alv,   // (R, FCOLS)
                                const float* __restrict__ arv,
                                ushort* __restrict__ fb0,
                                ushort* __restrict__ fb1,
                                float* __restrict__ el0,
                                float* __restrict__ er0,
                                float* __restrict__ el1,
                                float* __restrict__ er1,
                                int n) {
    constexpr int S  = 2 * K + 16;   // padded row stride in bytes
    constexpr int G  = K / 8;        // 16B granules per row
    constexpr int KS = K / 32;       // mfma k-steps
    __shared__ char lds[2 * 128 * S];
    char* Xs = lds;
    char* Ws = lds + 128 * S;
    const int tid = threadIdx.x;
    const int n0 = blockIdx.x * 128;

    for (int i = tid; i < 128 * G; i += 256) {
        int row = i / G, gk = i - row * G;
        int sr = n0 + row; if (sr >= n) sr = n - 1;
        *(uint4*)(Xs + row * S + gk * 16) =
            *(const uint4*)(Xbf + (size_t)sr * K + gk * 8);
    }
    __syncthreads();

    const int w    = tid >> 6;
    const int lane = tid & 63;
    const int c16  = lane & 15;
    const int rg   = lane >> 4;

    // A-fragments: relation-invariant, loaded once.
    bf16x8 afr[2][KS];
#pragma unroll
    for (int rt = 0; rt < 2; rt++)
#pragma unroll
        for (int ks = 0; ks < KS; ks++)
            afr[rt][ks] = *(const bf16x8*)(Xs + (w * 32 + rt * 16 + c16) * S + ks * 64 + rg * 16);

    for (int rel = 0; rel < 2; rel++) {
        if (rel) __syncthreads();   // prior relation's Ws reads complete
        const ushort* Wr = Wt + (size_t)rel * FCOLS * K;
        for (int i = tid; i < 128 * G; i += 256) {
            int row = i / G, gk = i - row * G;
            *(uint4*)(Ws + row * S + gk * 16) =
                *(const uint4*)(Wr + (size_t)row * K + gk * 8);
        }
        __syncthreads();

        f32x4 acc[2][8];
#pragma unroll
        for (int rt = 0; rt < 2; rt++)
#pragma unroll
            for (int ct = 0; ct < 8; ct++) acc[rt][ct] = (f32x4){0.f, 0.f, 0.f, 0.f};

#pragma unroll
        for (int ct = 0; ct < 8; ct++) {
#pragma unroll
            for (int ks = 0; ks < KS; ks++) {
                bf16x8 bfr = *(const bf16x8*)(Ws + (ct * 16 + c16) * S + ks * 64 + rg * 16);
                acc[0][ct] = __builtin_amdgcn_mfma_f32_16x16x32_bf16(afr[0][ks], bfr, acc[0][ct], 0, 0, 0);
                acc[1][ct] = __builtin_amdgcn_mfma_f32_16x16x32_bf16(afr[1][ks], bfr, acc[1][ct], 0, 0, 0);
            }
        }

        // epilogue: bf16 feat store + fused el/er for this relation
        const float* alr = alv + rel * FCOLS;
        const float* arr = arv + rel * FCOLS;
        ushort* featb = rel ? fb1 : fb0;
        float* el = rel ? el1 : el0;
        float* er = rel ? er1 : er0;

        float alq[8], arq[8];
#pragma unroll
        for (int ct = 0; ct < 8; ct++) {
            alq[ct] = alr[ct * 16 + c16];
            arq[ct] = arr[ct * 16 + c16];
        }

#pragma unroll
        for (int rt = 0; rt < 2; rt++) {
            float pel[2][4] = {{0.f,0.f,0.f,0.f},{0.f,0.f,0.f,0.f}};
            float per_[2][4] = {{0.f,0.f,0.f,0.f},{0.f,0.f,0.f,0.f}};
            const int nb = n0 + w * 32 + rt * 16 + rg * 4;
#pragma unroll
            for (int ct = 0; ct < 8; ct++) {
                const int h = ct >> 2;
#pragma unroll
                for (int r = 0; r < 4; r++) {
                    float v = acc[rt][ct][r];
                    pel[h][r]  = fmaf(v, alq[ct], pel[h][r]);
                    per_[h][r] = fmaf(v, arq[ct], per_[h][r]);
                    int node = nb + r;
                    if (node < n) featb[(size_t)node * 128 + ct * 16 + c16] = f2bf(v);
                }
            }
#pragma unroll
            for (int m = 8; m >= 1; m >>= 1) {
#pragma unroll
                for (int h = 0; h < 2; h++)
#pragma unroll
                    for (int r = 0; r < 4; r++) {
                        pel[h][r]  += __shfl_xor(pel[h][r], m);
                        per_[h][r] += __shfl_xor(per_[h][r], m);
                    }
            }
            if (c16 == 0) {
#pragma unroll
                for (int r = 0; r < 4; r++) {
                    int node = nb + r;
                    if (node < n) {
#pragma unroll
                        for (int h = 0; h < 2; h++) {
                            el[node * 2 + h] = pel[h][r];
                            er[node * 2 + h] = per_[h][r];
                        }
                    }
                }
            }
        }
    }
}

// ---------------------------------------------------------------------------
// CSR build over the CONCATENATED relations, XCD-partitioned (see R4 notes).
// ---------------------------------------------------------------------------
#define EDGE_CHUNK 2048

__global__ void zero_counts_kernel(int* __restrict__ counts, int n) {
    int i = blockIdx.x * blockDim.x + threadIdx.x;
    if (i < n) counts[i] = 0;
}

__global__ void count_xcd_kernel(const int* __restrict__ dst,
                                 int* __restrict__ counts,
                                 int E, int N, int kpp) {
    int part = blockIdx.x & 7;
    int base = (blockIdx.x >> 3) * EDGE_CHUNK + threadIdx.x;
    int total = 2 * E;
#pragma unroll
    for (int j = 0; j < 8; j++) {
        int i = base + j * 256;
        if (i < total) {
            int key = ((i >= E) ? N : 0) + dst[i];
            if (key / kpp == part) atomicAdd(&counts[key], 1);
        }
    }
}

#define SCAN_CHUNK 2048
#define SCAN_BT 256

__global__ void scan_blocksum_kernel(const int* __restrict__ counts,
                                     int* __restrict__ bsum, int n) {
    int b = blockIdx.x, t = threadIdx.x;
    int base = b * SCAN_CHUNK + t * 8;
    int s = 0;
#pragma unroll
    for (int j = 0; j < 8; j++) {
        int i = base + j;
        if (i < n) s += counts[i];
    }
    __shared__ int sd[SCAN_BT];
    sd[t] = s;
    __syncthreads();
    for (int off = SCAN_BT / 2; off > 0; off >>= 1) {
        if (t < off) sd[t] += sd[t + off];
        __syncthreads();
    }
    if (t == 0) bsum[b] = sd[0];
}

__global__ void scan_bsum_kernel(int* __restrict__ bsum, int* __restrict__ S,
                                 int B, int n) {
    __shared__ int sd[1024];
    int t = threadIdx.x;
    int v = (t < B) ? bsum[t] : 0;
    sd[t] = v;
    __syncthreads();
    for (int off = 1; off < 1024; off <<= 1) {
        int u = (t >= off) ? sd[t - off] : 0;
        __syncthreads();
        sd[t] = sd[t] + u;
        __syncthreads();
    }
    if (t < B) bsum[t] = sd[t] - v;
    if (t == 1023) S[n] = sd[1023];
}

__global__ void scan_write_kernel(const int* __restrict__ counts,
                                  const int* __restrict__ bsum,
                                  int* __restrict__ S, int* __restrict__ cursor,
                                  int n) {
    int b = blockIdx.x, t = threadIdx.x;
    int base = b * SCAN_CHUNK + t * 8;
    int v[8];
    int s = 0;
#pragma unroll
    for (int j = 0; j < 8; j++) {
        int i = base + j;
        v[j] = (i < n) ? counts[i] : 0;
        s += v[j];
    }
    __shared__ int sd[SCAN_BT];
    sd[t] = s;
    __syncthreads();
    for (int off = 1; off < SCAN_BT; off <<= 1) {
        int u = (t >= off) ? sd[t - off] : 0;
        __syncthreads();
        sd[t] = sd[t] + u;
        __syncthreads();
    }
    int run = bsum[b] + sd[t] - s;
#pragma unroll
    for (int j = 0; j < 8; j++) {
        int i = base + j;
        if (i < n) {
            S[i] = run;
            cursor[i] = run;
            run += v[j];
        }
    }
}

__global__ void fill_xcd_kernel(const int* __restrict__ src,
                                const int* __restrict__ dst,
                                int* __restrict__ cursor,
                                int* __restrict__ csr_src,
                                int E, int N, int kpp) {
    int part = blockIdx.x & 7;
    int base = (blockIdx.x >> 3) * EDGE_CHUNK + threadIdx.x;
    int total = 2 * E;
#pragma unroll
    for (int j = 0; j < 8; j++) {
        int i = base + j * 256;
        if (i < total) {
            int key = ((i >= E) ? N : 0) + dst[i];
            if (key / kpp == part) {
                int pos = atomicAdd(&cursor[key], 1);
                csr_src[pos] = src[i];
            }
        }
    }
}

// ---------------------------------------------------------------------------
// Fused both-relation GAT aggregation: one 64-lane wave per destination node.
// No-max softmax; LDS meta staging; unroll-8; packed 2xbf16 output.
// ---------------------------------------------------------------------------
#define AGG_BODY(J) {                                                        \
        int2 mp = lmeta[mbase + (J)];                                        \
        float a0 = __uint_as_float((unsigned)mp.y & 0xFFFF0000u);            \
        float a1 = __uint_as_float((unsigned)mp.y << 16);                    \
        den0 += a0;                                                          \
        den1 += a1;                                                          \
        float a = (h == 0) ? a0 : a1;                                        \
        unsigned fv = fbl[(size_t)mp.x * 64];                                \
        accx = fmaf(a, __uint_as_float((fv & 0xFFFFu) << 16), accx);         \
        accy = fmaf(a, __uint_as_float(fv & 0xFFFF0000u), accy);             \
    }

__launch_bounds__(256)
__global__ void gat_aggregate2_kernel(const int* __restrict__ S,
                                      const int* __restrict__ csrc,
                                      const float* __restrict__ el0,
                                      const float* __restrict__ er0,
                                      const float* __restrict__ el1,
                                      const float* __restrict__ er1,
                                      const unsigned* __restrict__ fb0,
                                      const unsigned* __restrict__ fb1,
                                      const float* __restrict__ ba,
                                      const float* __restrict__ bb,
                                      unsigned* __restrict__ hout,
                                      int N) {
    __shared__ int2 lmeta[4 * 64];
    int node = blockIdx.x * 4 + (threadIdx.x >> 6);
    if (node >= N) return;
    int lane = threadIdx.x & 63;
    int h = lane >> 5;
    const int mbase = (threadIdx.x >> 6) * 64;

    float accTx = 0.f, accTy = 0.f;
#pragma unroll
    for (int rel = 0; rel < 2; rel++) {
        const float* el = rel ? el1 : el0;
        const float* er = rel ? er1 : er0;
        const unsigned* fbl = (rel ? fb1 : fb0) + lane;
        int rs = S[rel * N + node], re = S[rel * N + node + 1];
        float erv0 = er[node * 2], erv1 = er[node * 2 + 1];
        float accx = 0.f, accy = 0.f;
        float den0 = 0.f, den1 = 0.f;

        for (int base = rs; base < re; base += 64) {
            int c = re - base; if (c > 64) c = 64;
            int msrc = 0;
            unsigned pex = 0;
            if (lane < c) {
                msrc = csrc[base + lane];
                float2 a = *reinterpret_cast<const float2*>(el + (size_t)msrc * 2);
                float s0 = a.x + erv0; s0 = s0 > 0.f ? s0 : 0.2f * s0;
                float s1 = a.y + erv1; s1 = s1 > 0.f ? s1 : 0.2f * s1;
                pex = ((unsigned)f2bf(__expf(s0)) << 16) | (unsigned)f2bf(__expf(s1));
            }
            lmeta[mbase + lane] = make_int2(msrc, (int)pex);
            int j = 0;
            for (; j + 7 < c; j += 8) {
                AGG_BODY(j)     AGG_BODY(j + 1) AGG_BODY(j + 2) AGG_BODY(j + 3)
                AGG_BODY(j + 4) AGG_BODY(j + 5) AGG_BODY(j + 6) AGG_BODY(j + 7)
            }
            for (; j + 3 < c; j += 4) {
                AGG_BODY(j) AGG_BODY(j + 1) AGG_BODY(j + 2) AGG_BODY(j + 3)
            }
            for (; j < c; ++j) AGG_BODY(j)
        }
        float den = (h == 0) ? den0 : den1;
        float invd = (den > 0.f) ? 1.f / den : 0.f;
        accTx += accx * invd;
        accTy += accy * invd;
    }

    float2 b1v = reinterpret_cast<const float2*>(ba)[lane];
    float2 b2v = reinterpret_cast<const float2*>(bb)[lane];
    float ox = b1v.x + b2v.x + accTx;
    float oy = b1v.y + b2v.y + accTy;
    hout[(size_t)node * 64 + lane] =
        ((unsigned)f2bf(oy) << 16) | (unsigned)f2bf(ox);
}

// ---------------------------------------------------------------------------
// Hout (n x 64) = [relu]( Hin(bf16, n x 128) @ Wl (128 x 64) + bl )
// BF16OUT: store bf16 (feeds next layer's MFMA gemm); else f32.
// ---------------------------------------------------------------------------
template <bool RELU, bool BF16OUT>
__launch_bounds__(256)
__global__ void linear_kernel(const ushort* __restrict__ Hin, const float* __restrict__ Wl,
                              const float* __restrict__ bl, float* __restrict__ Hout,
                              ushort* __restrict__ HoutBf, int n) {
    __shared__ float4 Wl4[128 * 16];  // 128 rows x 64 cols = 32 KB
    const int tid = threadIdx.x;
    const float4* W4 = reinterpret_cast<const float4*>(Wl);
    for (int i = tid; i < 128 * 16; i += 256) Wl4[i] = W4[i];
    __syncthreads();

    const int cg = tid & 15;   // column group (4 cols of 64)
    const int ng = tid >> 4;   // node subgroup 0..15
    const int n0 = blockIdx.x * 64 + ng * 4;

    const float4 bv = reinterpret_cast<const float4*>(bl)[cg];
    float4 acc[4];
#pragma unroll
    for (int i = 0; i < 4; i++) acc[i] = bv;

    const uint4* xrow[4];
#pragma unroll
    for (int i = 0; i < 4; i++) {
        int nn = n0 + i;
        int nc = nn < n ? nn : (n - 1);
        xrow[i] = reinterpret_cast<const uint4*>(Hin + (size_t)nc * 128);  // 16 uint4/row
    }

    for (int g = 0; g < 16; ++g) {   // 8 bf16 elems per granule
        uint4 xv[4];
#pragma unroll
        for (int i = 0; i < 4; i++) xv[i] = xrow[i][g];
#pragma unroll
        for (int j = 0; j < 8; j++) {
            float4 wv = Wl4[(g * 8 + j) * 16 + cg];
#pragma unroll
            for (int i = 0; i < 4; i++) {
                unsigned word = (j >> 1) == 0 ? xv[i].x : (j >> 1) == 1 ? xv[i].y
                              : (j >> 1) == 2 ? xv[i].z : xv[i].w;
                float xs = __uint_as_float((j & 1) ? (word & 0xFFFF0000u) : (word << 16));
                acc[i].x = fmaf(xs, wv.x, acc[i].x);
                acc[i].y = fmaf(xs, wv.y, acc[i].y);
                acc[i].z = fmaf(xs, wv.z, acc[i].z);
                acc[i].w = fmaf(xs, wv.w, acc[i].w);
            }
        }
    }

#pragma unroll
    for (int i = 0; i < 4; i++) {
        int nn = n0 + i;
        if (nn < n) {
            float4 v = acc[i];
            if (RELU) {
                v.x = fmaxf(v.x, 0.f); v.y = fmaxf(v.y, 0.f);
                v.z = fmaxf(v.z, 0.f); v.w = fmaxf(v.w, 0.f);
            }
            if (BF16OUT) {
                ushort4 o;
                o.x = f2bf(v.x); o.y = f2bf(v.y); o.z = f2bf(v.z); o.w = f2bf(v.w);
                reinterpret_cast<ushort4*>(HoutBf)[(size_t)nn * 16 + cg] = o;
            } else {
                reinterpret_cast<float4*>(Hout)[(size_t)nn * 16 + cg] = v;
            }
        }
    }
}

// ---------------------------------------------------------------------------
extern "C" void kernel_launch(void* const* d_in, const int* in_sizes, int n_in,
                              void* d_out, int out_size, void* d_ws, size_t ws_size,
                              hipStream_t stream) {
    const float* x    = (const float*)d_in[0];
    const int*   src  = (const int*)d_in[1];
    const int*   dst  = (const int*)d_in[2];
    const float* W0   = (const float*)d_in[3];
    const float* al0  = (const float*)d_in[4];
    const float* ar0  = (const float*)d_in[5];
    const float* b0   = (const float*)d_in[6];
    const float* W1   = (const float*)d_in[7];
    const float* al1  = (const float*)d_in[8];
    const float* ar1  = (const float*)d_in[9];
    const float* b1   = (const float*)d_in[10];
    const float* linW0 = (const float*)d_in[11];
    const float* linb0 = (const float*)d_in[12];
    const float* linW1 = (const float*)d_in[13];
    const float* linb1 = (const float*)d_in[14];
    float* out = (float*)d_out;

    const int N = in_sizes[0] / IN_DIM;
    const int E = in_sizes[1] / R_REL;
    const int n2 = 2 * N;
    const int kpp = (n2 + 7) / 8;  // keys per XCD partition

    // workspace layout (hbuf slot kept at N*128 floats; only half used now)
    float* ws   = (float*)d_ws;
    float* hbuf = ws;                          // N*64 uint (2xbf16 packed)
    float* el0  = hbuf + (size_t)N * 128;      // N*2
    float* er0  = el0 + (size_t)N * 2;         // N*2
    float* el1  = er0 + (size_t)N * 2;         // N*2
    float* er1  = el1 + (size_t)N * 2;         // N*2
    ushort* Xbf    = (ushort*)(er1 + (size_t)N * 2);    // N*128 bf16
    ushort* featb0 = Xbf + (size_t)N * 128;             // N*128 bf16
    ushort* featb1 = featb0 + (size_t)N * 128;          // N*128 bf16
    ushort* hmidbf = featb1 + (size_t)N * 128;          // N*64 bf16
    ushort* Wt0    = hmidbf + (size_t)N * 64;           // 2*128*128 bf16
    ushort* Wt1    = Wt0 + (size_t)2 * FCOLS * IN_DIM;  // 2*128*64 bf16
    int* counts = (int*)(Wt1 + (size_t)2 * FCOLS * HID_DIM);  // 2N
    int* S      = counts + (size_t)n2;             // 2N+1
    int* cursor = S + (size_t)(n2 + 1);            // 2N
    int* bsum   = cursor + (size_t)n2;             // up to 1024
    int* csrsrc = bsum + 1024;                     // 2E

    const int TB = 256;
    const int bmf = (N + 127) / 128;
    const int bagg = (N + 3) / 4;
    const int blin = (N + 63) / 64;
    const int b2n = (n2 + TB - 1) / TB;
    const int nchunk = (2 * E + EDGE_CHUNK - 1) / EDGE_CHUNK;
    const int bscan = (n2 + SCAN_CHUNK - 1) / SCAN_CHUNK;

    // ---------------- prep: bf16 conversions (once per call) --------------
    const int xtotal4 = N * IN_DIM / 4;
    cvt_bf16_kernel<<<(xtotal4 + TB - 1) / TB, TB, 0, stream>>>(x, Xbf, xtotal4);
    wt_kernel<IN_DIM><<<(2 * IN_DIM * FCOLS) / 256, 256, 0, stream>>>(W0, Wt0);
    wt_kernel<HID_DIM><<<(2 * HID_DIM * FCOLS) / 256, 256, 0, stream>>>(W1, Wt1);

    // ---------------- CSR build (once; shared by both layers) -------------
    zero_counts_kernel<<<b2n, TB, 0, stream>>>(counts, n2);
    count_xcd_kernel<<<nchunk * 8, TB, 0, stream>>>(dst, counts, E, N, kpp);
    scan_blocksum_kernel<<<bscan, SCAN_BT, 0, stream>>>(counts, bsum, n2);
    scan_bsum_kernel<<<1, 1024, 0, stream>>>(bsum, S, bscan, n2);
    scan_write_kernel<<<bscan, SCAN_BT, 0, stream>>>(counts, bsum, S, cursor, n2);
    fill_xcd_kernel<<<nchunk * 8, TB, 0, stream>>>(src, dst, cursor, csrsrc, E, N, kpp);

    // ---------------- layer 0 ----------------
    feat_gemm_mfma2<IN_DIM><<<bmf, TB, 0, stream>>>(Xbf, Wt0, al0, ar0,
                                                    featb0, featb1, el0, er0, el1, er1, N);
    gat_aggregate2_kernel<<<bagg, TB, 0, stream>>>(S, csrsrc, el0, er0, el1, er1,
                                                   (const unsigned*)featb0, (const unsigned*)featb1,
                                                   b0, b0 + 128, (unsigned*)hbuf, N);
    linear_kernel<true, true><<<blin, TB, 0, stream>>>((const ushort*)hbuf, linW0, linb0,
                                                       nullptr, hmidbf, N);

    // ---------------- layer 1 ----------------
    feat_gemm_mfma2<HID_DIM><<<bmf, TB, 0, stream>>>(hmidbf, Wt1, al1, ar1,
                                                     featb0, featb1, el0, er0, el1, er1, N);
    gat_aggregate2_kernel<<<bagg, TB, 0, stream>>>(S, csrsrc, el0, er0, el1, er1,
                                                   (const unsigned*)featb0, (const unsigned*)featb1,
                                                   b1, b1 + 128, (unsigned*)hbuf, N);
    linear_kernel<false, false><<<blin, TB, 0, stream>>>((const ushort*)hbuf, linW1, linb1,
                                                         out, nullptr, N);
}

// Round 18
// 447.741 us; speedup vs baseline: 1.1354x; 1.0219x over previous
//
#include <hip/hip_runtime.h>
#include <math.h>

// Problem constants (match reference)
#define R_REL 2
#define IN_DIM 128
#define HID_DIM 64
#define FCOLS 128

typedef __attribute__((ext_vector_type(8))) short bf16x8;
typedef __attribute__((ext_vector_type(4))) float f32x4;

__device__ __forceinline__ ushort f2bf(float f) {
    unsigned u = __float_as_uint(f);
    u += 0x7FFFu + ((u >> 16) & 1u);   // round-to-nearest-even
    return (ushort)(u >> 16);
}

// Prep: W (R, K, FCOLS f32) -> Wt (R, FCOLS, K bf16)  (transpose + convert)
template <int K>
__global__ void wt_kernel(const float* __restrict__ W, ushort* __restrict__ Wt) {
    int i = blockIdx.x * 256 + threadIdx.x;       // grid covers R*K*FCOLS exactly
    int r = i / (K * FCOLS);
    int rem = i - r * (K * FCOLS);
    int k = rem / FCOLS, c = rem - k * FCOLS;
    Wt[((size_t)r * FCOLS + c) * K + k] = f2bf(W[i]);
}

// ---------------------------------------------------------------------------
// Fused both-relation MFMA feat-GEMM: feat_r(bf16) = X @ W_r, r=0,1, with
// fused el/er epilogues. X staged ONCE in LDS (F32IN: converted f32->bf16
// in-register during staging — deletes the standalone cvt kernel) and
// A-fragments loaded ONCE (relation-invariant); per relation only W re-staged.
// Block: 256 thr = 4 waves, 128 nodes/block; rows padded +16B.
// mfma_f32_16x16x32_bf16: A row=lane&15, k=(lane>>4)*8+e; B col=lane&15;
// D col=lane&15, row=(lane>>4)*4+r (verified layout, learn_hip m89).
// ---------------------------------------------------------------------------
template <int K, bool F32IN>
__launch_bounds__(256)
__global__ void feat_gemm_mfma2(const void* __restrict__ Xin,
                                const ushort* __restrict__ Wt,   // both relations
                                const float* __restrict__ alv,   // (R, FCOLS)
                                const float* __restrict__ arv,
                                ushort* __restrict__ fb0,
                                ushort* __restrict__ fb1,
                                float* __restrict__ el0,
                                float* __restrict__ er0,
                                float* __restrict__ el1,
                                float* __restrict__ er1,
                                int n) {
    constexpr int S  = 2 * K + 16;   // padded row stride in bytes
    constexpr int G  = K / 8;        // 16B (8-elem bf16) granules per row
    constexpr int KS = K / 32;       // mfma k-steps
    __shared__ char lds[2 * 128 * S];
    char* Xs = lds;
    char* Ws = lds + 128 * S;
    const int tid = threadIdx.x;
    const int n0 = blockIdx.x * 128;

    for (int i = tid; i < 128 * G; i += 256) {
        int row = i / G, gk = i - row * G;
        int sr = n0 + row; if (sr >= n) sr = n - 1;
        if (F32IN) {
            const float* xr = (const float*)Xin + (size_t)sr * K + gk * 8;
            float4 a = *(const float4*)(xr);
            float4 b = *(const float4*)(xr + 4);
            ushort4 lo = {f2bf(a.x), f2bf(a.y), f2bf(a.z), f2bf(a.w)};
            ushort4 hi = {f2bf(b.x), f2bf(b.y), f2bf(b.z), f2bf(b.w)};
            *(ushort4*)(Xs + row * S + gk * 16) = lo;
            *(ushort4*)(Xs + row * S + gk * 16 + 8) = hi;
        } else {
            *(uint4*)(Xs + row * S + gk * 16) =
                *(const uint4*)((const ushort*)Xin + (size_t)sr * K + gk * 8);
        }
    }
    __syncthreads();

    const int w    = tid >> 6;
    const int lane = tid & 63;
    const int c16  = lane & 15;
    const int rg   = lane >> 4;

    // A-fragments: relation-invariant, loaded once.
    bf16x8 afr[2][KS];
#pragma unroll
    for (int rt = 0; rt < 2; rt++)
#pragma unroll
        for (int ks = 0; ks < KS; ks++)
            afr[rt][ks] = *(const bf16x8*)(Xs + (w * 32 + rt * 16 + c16) * S + ks * 64 + rg * 16);

    for (int rel = 0; rel < 2; rel++) {
        if (rel) __syncthreads();   // prior relation's Ws reads complete
        const ushort* Wr = Wt + (size_t)rel * FCOLS * K;
        for (int i = tid; i < 128 * G; i += 256) {
            int row = i / G, gk = i - row * G;
            *(uint4*)(Ws + row * S + gk * 16) =
                *(const uint4*)(Wr + (size_t)row * K + gk * 8);
        }
        __syncthreads();

        f32x4 acc[2][8];
#pragma unroll
        for (int rt = 0; rt < 2; rt++)
#pragma unroll
            for (int ct = 0; ct < 8; ct++) acc[rt][ct] = (f32x4){0.f, 0.f, 0.f, 0.f};

#pragma unroll
        for (int ct = 0; ct < 8; ct++) {
#pragma unroll
            for (int ks = 0; ks < KS; ks++) {
                bf16x8 bfr = *(const bf16x8*)(Ws + (ct * 16 + c16) * S + ks * 64 + rg * 16);
                acc[0][ct] = __builtin_amdgcn_mfma_f32_16x16x32_bf16(afr[0][ks], bfr, acc[0][ct], 0, 0, 0);
                acc[1][ct] = __builtin_amdgcn_mfma_f32_16x16x32_bf16(afr[1][ks], bfr, acc[1][ct], 0, 0, 0);
            }
        }

        // epilogue: bf16 feat store + fused el/er for this relation
        const float* alr = alv + rel * FCOLS;
        const float* arr = arv + rel * FCOLS;
        ushort* featb = rel ? fb1 : fb0;
        float* el = rel ? el1 : el0;
        float* er = rel ? er1 : er0;

        float alq[8], arq[8];
#pragma unroll
        for (int ct = 0; ct < 8; ct++) {
            alq[ct] = alr[ct * 16 + c16];
            arq[ct] = arr[ct * 16 + c16];
        }

#pragma unroll
        for (int rt = 0; rt < 2; rt++) {
            float pel[2][4] = {{0.f,0.f,0.f,0.f},{0.f,0.f,0.f,0.f}};
            float per_[2][4] = {{0.f,0.f,0.f,0.f},{0.f,0.f,0.f,0.f}};
            const int nb = n0 + w * 32 + rt * 16 + rg * 4;
#pragma unroll
            for (int ct = 0; ct < 8; ct++) {
                const int h = ct >> 2;
#pragma unroll
                for (int r = 0; r < 4; r++) {
                    float v = acc[rt][ct][r];
                    pel[h][r]  = fmaf(v, alq[ct], pel[h][r]);
                    per_[h][r] = fmaf(v, arq[ct], per_[h][r]);
                    int node = nb + r;
                    if (node < n) featb[(size_t)node * 128 + ct * 16 + c16] = f2bf(v);
                }
            }
#pragma unroll
            for (int m = 8; m >= 1; m >>= 1) {
#pragma unroll
                for (int h = 0; h < 2; h++)
#pragma unroll
                    for (int r = 0; r < 4; r++) {
                        pel[h][r]  += __shfl_xor(pel[h][r], m);
                        per_[h][r] += __shfl_xor(per_[h][r], m);
                    }
            }
            if (c16 == 0) {
#pragma unroll
                for (int r = 0; r < 4; r++) {
                    int node = nb + r;
                    if (node < n) {
#pragma unroll
                        for (int h = 0; h < 2; h++) {
                            el[node * 2 + h] = pel[h][r];
                            er[node * 2 + h] = per_[h][r];
                        }
                    }
                }
            }
        }
    }
}

// ---------------------------------------------------------------------------
// CSR build over the CONCATENATED relations, XCD-partitioned (see R4 notes).
// ---------------------------------------------------------------------------
#define EDGE_CHUNK 2048

__global__ void zero_counts_kernel(int* __restrict__ counts, int n) {
    int i = blockIdx.x * blockDim.x + threadIdx.x;
    if (i < n) counts[i] = 0;
}

__global__ void count_xcd_kernel(const int* __restrict__ dst,
                                 int* __restrict__ counts,
                                 int E, int N, int kpp) {
    int part = blockIdx.x & 7;
    int base = (blockIdx.x >> 3) * EDGE_CHUNK + threadIdx.x;
    int total = 2 * E;
#pragma unroll
    for (int j = 0; j < 8; j++) {
        int i = base + j * 256;
        if (i < total) {
            int key = ((i >= E) ? N : 0) + dst[i];
            if (key / kpp == part) atomicAdd(&counts[key], 1);
        }
    }
}

#define SCAN_CHUNK 2048
#define SCAN_BT 256

__global__ void scan_blocksum_kernel(const int* __restrict__ counts,
                                     int* __restrict__ bsum, int n) {
    int b = blockIdx.x, t = threadIdx.x;
    int base = b * SCAN_CHUNK + t * 8;
    int s = 0;
#pragma unroll
    for (int j = 0; j < 8; j++) {
        int i = base + j;
        if (i < n) s += counts[i];
    }
    __shared__ int sd[SCAN_BT];
    sd[t] = s;
    __syncthreads();
    for (int off = SCAN_BT / 2; off > 0; off >>= 1) {
        if (t < off) sd[t] += sd[t + off];
        __syncthreads();
    }
    if (t == 0) bsum[b] = sd[0];
}

__global__ void scan_bsum_kernel(int* __restrict__ bsum, int* __restrict__ S,
                                 int B, int n) {
    __shared__ int sd[1024];
    int t = threadIdx.x;
    int v = (t < B) ? bsum[t] : 0;
    sd[t] = v;
    __syncthreads();
    for (int off = 1; off < 1024; off <<= 1) {
        int u = (t >= off) ? sd[t - off] : 0;
        __syncthreads();
        sd[t] = sd[t] + u;
        __syncthreads();
    }
    if (t < B) bsum[t] = sd[t] - v;
    if (t == 1023) S[n] = sd[1023];
}

__global__ void scan_write_kernel(const int* __restrict__ counts,
                                  const int* __restrict__ bsum,
                                  int* __restrict__ S, int* __restrict__ cursor,
                                  int n) {
    int b = blockIdx.x, t = threadIdx.x;
    int base = b * SCAN_CHUNK + t * 8;
    int v[8];
    int s = 0;
#pragma unroll
    for (int j = 0; j < 8; j++) {
        int i = base + j;
        v[j] = (i < n) ? counts[i] : 0;
        s += v[j];
    }
    __shared__ int sd[SCAN_BT];
    sd[t] = s;
    __syncthreads();
    for (int off = 1; off < SCAN_BT; off <<= 1) {
        int u = (t >= off) ? sd[t - off] : 0;
        __syncthreads();
        sd[t] = sd[t] + u;
        __syncthreads();
    }
    int run = bsum[b] + sd[t] - s;
#pragma unroll
    for (int j = 0; j < 8; j++) {
        int i = base + j;
        if (i < n) {
            S[i] = run;
            cursor[i] = run;
            run += v[j];
        }
    }
}

__global__ void fill_xcd_kernel(const int* __restrict__ src,
                                const int* __restrict__ dst,
                                int* __restrict__ cursor,
                                int* __restrict__ csr_src,
                                int E, int N, int kpp) {
    int part = blockIdx.x & 7;
    int base = (blockIdx.x >> 3) * EDGE_CHUNK + threadIdx.x;
    int total = 2 * E;
#pragma unroll
    for (int j = 0; j < 8; j++) {
        int i = base + j * 256;
        if (i < total) {
            int key = ((i >= E) ? N : 0) + dst[i];
            if (key / kpp == part) {
                int pos = atomicAdd(&cursor[key], 1);
                csr_src[pos] = src[i];
            }
        }
    }
}

// ---------------------------------------------------------------------------
// Fused both-relation GAT aggregation: one 64-lane wave per destination node.
// No-max softmax; LDS meta staging; unroll-8; packed 2xbf16 output.
// (At the random-gather fabric floor: 244 MB L2-miss traffic @ ~2.8 TB/s.)
// ---------------------------------------------------------------------------
#define AGG_BODY(J) {                                                        \
        int2 mp = lmeta[mbase + (J)];                                        \
        float a0 = __uint_as_float((unsigned)mp.y & 0xFFFF0000u);            \
        float a1 = __uint_as_float((unsigned)mp.y << 16);                    \
        den0 += a0;                                                          \
        den1 += a1;                                                          \
        float a = (h == 0) ? a0 : a1;                                        \
        unsigned fv = fbl[(size_t)mp.x * 64];                                \
        accx = fmaf(a, __uint_as_float((fv & 0xFFFFu) << 16), accx);         \
        accy = fmaf(a, __uint_as_float(fv & 0xFFFF0000u), accy);             \
    }

__launch_bounds__(256)
__global__ void gat_aggregate2_kernel(const int* __restrict__ S,
                                      const int* __restrict__ csrc,
                                      const float* __restrict__ el0,
                                      const float* __restrict__ er0,
                                      const float* __restrict__ el1,
                                      const float* __restrict__ er1,
                                      const unsigned* __restrict__ fb0,
                                      const unsigned* __restrict__ fb1,
                                      const float* __restrict__ ba,
                                      const float* __restrict__ bb,
                                      unsigned* __restrict__ hout,
                                      int N) {
    __shared__ int2 lmeta[4 * 64];
    int node = blockIdx.x * 4 + (threadIdx.x >> 6);
    if (node >= N) return;
    int lane = threadIdx.x & 63;
    int h = lane >> 5;
    const int mbase = (threadIdx.x >> 6) * 64;

    float accTx = 0.f, accTy = 0.f;
#pragma unroll
    for (int rel = 0; rel < 2; rel++) {
        const float* el = rel ? el1 : el0;
        const float* er = rel ? er1 : er0;
        const unsigned* fbl = (rel ? fb1 : fb0) + lane;
        int rs = S[rel * N + node], re = S[rel * N + node + 1];
        float erv0 = er[node * 2], erv1 = er[node * 2 + 1];
        float accx = 0.f, accy = 0.f;
        float den0 = 0.f, den1 = 0.f;

        for (int base = rs; base < re; base += 64) {
            int c = re - base; if (c > 64) c = 64;
            int msrc = 0;
            unsigned pex = 0;
            if (lane < c) {
                msrc = csrc[base + lane];
                float2 a = *reinterpret_cast<const float2*>(el + (size_t)msrc * 2);
                float s0 = a.x + erv0; s0 = s0 > 0.f ? s0 : 0.2f * s0;
                float s1 = a.y + erv1; s1 = s1 > 0.f ? s1 : 0.2f * s1;
                pex = ((unsigned)f2bf(__expf(s0)) << 16) | (unsigned)f2bf(__expf(s1));
            }
            lmeta[mbase + lane] = make_int2(msrc, (int)pex);
            int j = 0;
            for (; j + 7 < c; j += 8) {
                AGG_BODY(j)     AGG_BODY(j + 1) AGG_BODY(j + 2) AGG_BODY(j + 3)
                AGG_BODY(j + 4) AGG_BODY(j + 5) AGG_BODY(j + 6) AGG_BODY(j + 7)
            }
            for (; j + 3 < c; j += 4) {
                AGG_BODY(j) AGG_BODY(j + 1) AGG_BODY(j + 2) AGG_BODY(j + 3)
            }
            for (; j < c; ++j) AGG_BODY(j)
        }
        float den = (h == 0) ? den0 : den1;
        float invd = (den > 0.f) ? 1.f / den : 0.f;
        accTx += accx * invd;
        accTy += accy * invd;
    }

    float2 b1v = reinterpret_cast<const float2*>(ba)[lane];
    float2 b2v = reinterpret_cast<const float2*>(bb)[lane];
    float ox = b1v.x + b2v.x + accTx;
    float oy = b1v.y + b2v.y + accTy;
    hout[(size_t)node * 64 + lane] =
        ((unsigned)f2bf(oy) << 16) | (unsigned)f2bf(ox);
}

// ---------------------------------------------------------------------------
// Hout (n x 64) = [relu]( Hin(bf16, n x 128) @ Wl (128 x 64) + bl )
// BF16OUT: store bf16 (feeds next layer's MFMA gemm); else f32.
// ---------------------------------------------------------------------------
template <bool RELU, bool BF16OUT>
__launch_bounds__(256)
__global__ void linear_kernel(const ushort* __restrict__ Hin, const float* __restrict__ Wl,
                              const float* __restrict__ bl, float* __restrict__ Hout,
                              ushort* __restrict__ HoutBf, int n) {
    __shared__ float4 Wl4[128 * 16];  // 128 rows x 64 cols = 32 KB
    const int tid = threadIdx.x;
    const float4* W4 = reinterpret_cast<const float4*>(Wl);
    for (int i = tid; i < 128 * 16; i += 256) Wl4[i] = W4[i];
    __syncthreads();

    const int cg = tid & 15;   // column group (4 cols of 64)
    const int ng = tid >> 4;   // node subgroup 0..15
    const int n0 = blockIdx.x * 64 + ng * 4;

    const float4 bv = reinterpret_cast<const float4*>(bl)[cg];
    float4 acc[4];
#pragma unroll
    for (int i = 0; i < 4; i++) acc[i] = bv;

    const uint4* xrow[4];
#pragma unroll
    for (int i = 0; i < 4; i++) {
        int nn = n0 + i;
        int nc = nn < n ? nn : (n - 1);
        xrow[i] = reinterpret_cast<const uint4*>(Hin + (size_t)nc * 128);  // 16 uint4/row
    }

    for (int g = 0; g < 16; ++g) {   // 8 bf16 elems per granule
        uint4 xv[4];
#pragma unroll
        for (int i = 0; i < 4; i++) xv[i] = xrow[i][g];
#pragma unroll
        for (int j = 0; j < 8; j++) {
            float4 wv = Wl4[(g * 8 + j) * 16 + cg];
#pragma unroll
            for (int i = 0; i < 4; i++) {
                unsigned word = (j >> 1) == 0 ? xv[i].x : (j >> 1) == 1 ? xv[i].y
                              : (j >> 1) == 2 ? xv[i].z : xv[i].w;
                float xs = __uint_as_float((j & 1) ? (word & 0xFFFF0000u) : (word << 16));
                acc[i].x = fmaf(xs, wv.x, acc[i].x);
                acc[i].y = fmaf(xs, wv.y, acc[i].y);
                acc[i].z = fmaf(xs, wv.z, acc[i].z);
                acc[i].w = fmaf(xs, wv.w, acc[i].w);
            }
        }
    }

#pragma unroll
    for (int i = 0; i < 4; i++) {
        int nn = n0 + i;
        if (nn < n) {
            float4 v = acc[i];
            if (RELU) {
                v.x = fmaxf(v.x, 0.f); v.y = fmaxf(v.y, 0.f);
                v.z = fmaxf(v.z, 0.f); v.w = fmaxf(v.w, 0.f);
            }
            if (BF16OUT) {
                ushort4 o;
                o.x = f2bf(v.x); o.y = f2bf(v.y); o.z = f2bf(v.z); o.w = f2bf(v.w);
                reinterpret_cast<ushort4*>(HoutBf)[(size_t)nn * 16 + cg] = o;
            } else {
                reinterpret_cast<float4*>(Hout)[(size_t)nn * 16 + cg] = v;
            }
        }
    }
}

// ---------------------------------------------------------------------------
extern "C" void kernel_launch(void* const* d_in, const int* in_sizes, int n_in,
                              void* d_out, int out_size, void* d_ws, size_t ws_size,
                              hipStream_t stream) {
    const float* x    = (const float*)d_in[0];
    const int*   src  = (const int*)d_in[1];
    const int*   dst  = (const int*)d_in[2];
    const float* W0   = (const float*)d_in[3];
    const float* al0  = (const float*)d_in[4];
    const float* ar0  = (const float*)d_in[5];
    const float* b0   = (const float*)d_in[6];
    const float* W1   = (const float*)d_in[7];
    const float* al1  = (const float*)d_in[8];
    const float* ar1  = (const float*)d_in[9];
    const float* b1   = (const float*)d_in[10];
    const float* linW0 = (const float*)d_in[11];
    const float* linb0 = (const float*)d_in[12];
    const float* linW1 = (const float*)d_in[13];
    const float* linb1 = (const float*)d_in[14];
    float* out = (float*)d_out;

    const int N = in_sizes[0] / IN_DIM;
    const int E = in_sizes[1] / R_REL;
    const int n2 = 2 * N;
    const int kpp = (n2 + 7) / 8;  // keys per XCD partition

    // workspace layout
    float* ws   = (float*)d_ws;
    float* hbuf = ws;                          // N*64 uint (2xbf16 packed)
    float* el0  = hbuf + (size_t)N * 128;      // N*2
    float* er0  = el0 + (size_t)N * 2;         // N*2
    float* el1  = er0 + (size_t)N * 2;         // N*2
    float* er1  = el1 + (size_t)N * 2;         // N*2
    ushort* featb0 = (ushort*)(er1 + (size_t)N * 2);    // N*128 bf16
    ushort* featb1 = featb0 + (size_t)N * 128;          // N*128 bf16
    ushort* hmidbf = featb1 + (size_t)N * 128;          // N*64 bf16
    ushort* Wt0    = hmidbf + (size_t)N * 64;           // 2*128*128 bf16
    ushort* Wt1    = Wt0 + (size_t)2 * FCOLS * IN_DIM;  // 2*128*64 bf16
    int* counts = (int*)(Wt1 + (size_t)2 * FCOLS * HID_DIM);  // 2N
    int* S      = counts + (size_t)n2;             // 2N+1
    int* cursor = S + (size_t)(n2 + 1);            // 2N
    int* bsum   = cursor + (size_t)n2;             // up to 1024
    int* csrsrc = bsum + 1024;                     // 2E

    const int TB = 256;
    const int bmf = (N + 127) / 128;
    const int bagg = (N + 3) / 4;
    const int blin = (N + 63) / 64;
    const int b2n = (n2 + TB - 1) / TB;
    const int nchunk = (2 * E + EDGE_CHUNK - 1) / EDGE_CHUNK;
    const int bscan = (n2 + SCAN_CHUNK - 1) / SCAN_CHUNK;

    // ---------------- prep: weight transposes (once per call) -------------
    wt_kernel<IN_DIM><<<(2 * IN_DIM * FCOLS) / 256, 256, 0, stream>>>(W0, Wt0);
    wt_kernel<HID_DIM><<<(2 * HID_DIM * FCOLS) / 256, 256, 0, stream>>>(W1, Wt1);

    // ---------------- CSR build (once; shared by both layers) -------------
    zero_counts_kernel<<<b2n, TB, 0, stream>>>(counts, n2);
    count_xcd_kernel<<<nchunk * 8, TB, 0, stream>>>(dst, counts, E, N, kpp);
    scan_blocksum_kernel<<<bscan, SCAN_BT, 0, stream>>>(counts, bsum, n2);
    scan_bsum_kernel<<<1, 1024, 0, stream>>>(bsum, S, bscan, n2);
    scan_write_kernel<<<bscan, SCAN_BT, 0, stream>>>(counts, bsum, S, cursor, n2);
    fill_xcd_kernel<<<nchunk * 8, TB, 0, stream>>>(src, dst, cursor, csrsrc, E, N, kpp);

    // ---------------- layer 0 (f32 X converted in-staging) ----------------
    feat_gemm_mfma2<IN_DIM, true><<<bmf, TB, 0, stream>>>(x, Wt0, al0, ar0,
                                                          featb0, featb1, el0, er0, el1, er1, N);
    gat_aggregate2_kernel<<<bagg, TB, 0, stream>>>(S, csrsrc, el0, er0, el1, er1,
                                                   (const unsigned*)featb0, (const unsigned*)featb1,
                                                   b0, b0 + 128, (unsigned*)hbuf, N);
    linear_kernel<true, true><<<blin, TB, 0, stream>>>((const ushort*)hbuf, linW0, linb0,
                                                       nullptr, hmidbf, N);

    // ---------------- layer 1 ----------------
    feat_gemm_mfma2<HID_DIM, false><<<bmf, TB, 0, stream>>>(hmidbf, Wt1, al1, ar1,
                                                            featb0, featb1, el0, er0, el1, er1, N);
    gat_aggregate2_kernel<<<bagg, TB, 0, stream>>>(S, csrsrc, el0, er0, el1, er1,
                                                   (const unsigned*)featb0, (const unsigned*)featb1,
                                                   b1, b1 + 128, (unsigned*)hbuf, N);
    linear_kernel<false, false><<<blin, TB, 0, stream>>>((const ushort*)hbuf, linW1, linb1,
                                                         out, nullptr, N);
}